// Round 2
// 19621.158 us; speedup vs baseline: 1.1085x; 1.1085x over previous
//
#include <hip/hip_runtime.h>
#include <math.h>

typedef unsigned short u16;
typedef unsigned long long u64;
typedef __attribute__((ext_vector_type(8))) short s16x8;
typedef __attribute__((ext_vector_type(4))) short s16x4;
typedef __attribute__((ext_vector_type(4))) float f4v;

__device__ __forceinline__ float bf2f(short u) {
    union { unsigned int i; float f; } v;
    v.i = ((unsigned int)(u16)u) << 16;
    return v.f;
}
__device__ __forceinline__ u16 f2bf(float f) {
    union { float f; unsigned int i; } v; v.f = f;
    unsigned int x = v.i;
    return (u16)((x + 0x7FFFu + ((x >> 16) & 1u)) >> 16);
}

// agent-scope (cross-XCD coherent, L2-bypassing) 8B load / 2B store
__device__ __forceinline__ u64 coh_load_u64(const u16* p) {
    return __hip_atomic_load((const u64*)p, __ATOMIC_RELAXED, __HIP_MEMORY_SCOPE_AGENT);
}
__device__ __forceinline__ void coh_store_u16(u16* p, u16 v) {
    __hip_atomic_store(p, v, __ATOMIC_RELAXED, __HIP_MEMORY_SCOPE_AGENT);
}

// ---------------- device-wide barrier (monotonic counter) ----------------
// Release fence (writeback, NO invalidate) + relaxed atomics. Weights and all
// block-local state stay L2-resident across steps; cross-block h data travels
// via write-through atomic stores + L2-bypassing atomic loads instead.
__device__ __forceinline__ void grid_barrier(unsigned* bar, unsigned target) {
    __builtin_amdgcn_fence(__ATOMIC_RELEASE, "agent");   // waitcnt + wbl2 (no inv)
    if (threadIdx.x == 0)
        __hip_atomic_fetch_add(bar, 1u, __ATOMIC_RELAXED, __HIP_MEMORY_SCOPE_AGENT);
    int spins = 0;
    while (__hip_atomic_load(bar, __ATOMIC_RELAXED, __HIP_MEMORY_SCOPE_AGENT) < target) {
        __builtin_amdgcn_s_sleep(1);
        if (++spins > (1 << 20)) break;    // bail-out: avoid infinite hang
    }
    asm volatile("" ::: "memory");
}

__global__ void zero_bar(unsigned* p, int n) {
    if ((int)threadIdx.x < n) p[threadIdx.x] = 0;
}

// ---------------- fp32 -> bf16 weight conversion ----------------
__global__ __launch_bounds__(256)
void cvt_bf16v(const float* __restrict__ src, u16* __restrict__ dst, int n4) {
    int i = blockIdx.x * 256 + threadIdx.x;
    int stride = gridDim.x * 256;
    for (; i < n4; i += stride) {
        f4v v = ((const f4v*)src)[i];
        s16x4 o;
#pragma unroll
        for (int j = 0; j < 4; ++j) o[j] = (short)f2bf(v[j]);
        ((s16x4*)dst)[i] = o;
    }
}

// ---------------- layer0 input gates (one dir): xg = x @ W^T + bih, K=75 ----------------
__global__ __launch_bounds__(256)
void xg0_kernel(const float* __restrict__ x,   // [6400][75]
                const float* __restrict__ W,   // [3072][75] (this dir)
                const float* __restrict__ bih, // [3072]
                u16* __restrict__ xg)          // [6400][3072]
{
    const int bt0 = blockIdx.x * 16;
    __shared__ float xl[16][76];
    for (int idx = threadIdx.x; idx < 16 * 75; idx += 256) {
        int r = idx / 75, k = idx % 75;
        xl[r][k] = x[(size_t)(bt0 + r) * 75 + k];
    }
    __syncthreads();
    for (int i = 0; i < 12; ++i) {
        int g = threadIdx.x + i * 256;
        const float* wr = W + (size_t)g * 75;
        float bv = bih[g];
        float acc[16];
#pragma unroll
        for (int r = 0; r < 16; ++r) acc[r] = bv;
        for (int k = 0; k < 75; ++k) {
            float w = wr[k];
#pragma unroll
            for (int r = 0; r < 16; ++r) acc[r] += xl[r][k] * w;
        }
#pragma unroll
        for (int r = 0; r < 16; ++r)
            xg[(size_t)(bt0 + r) * 3072 + g] = f2bf(acc[r]);
    }
}

// ---------------- MFMA bt-GEMM: C[6400,3072] = A(bf16)[6400,K] @ B(fp32)[3072,K]^T + bias ----------------
__global__ __launch_bounds__(256)
void xg_gemm(const u16* __restrict__ A, const float* __restrict__ Bm,
             const float* __restrict__ bias, u16* __restrict__ C, int K)
{
    __shared__ u16 Alds[64 * 40];
    __shared__ u16 Blds[64 * 40];
    const int m0 = blockIdx.x * 64;
    const int n0 = blockIdx.y * 64;
    const int wave = threadIdx.x >> 6;
    const int lane = threadIdx.x & 63;
    const int r = threadIdx.x >> 2;
    const int kk = (threadIdx.x & 3) * 8;
    const int mrow = wave * 16 + (lane & 15);
    const int kq = (lane >> 4) * 8;
    f4v acc[4];
#pragma unroll
    for (int nt = 0; nt < 4; ++nt) acc[nt] = (f4v){0.f, 0.f, 0.f, 0.f};

    for (int k0 = 0; k0 < K; k0 += 32) {
        *(s16x8*)&Alds[r * 40 + kk] = *(const s16x8*)(A + (size_t)(m0 + r) * K + k0 + kk);
        f4v b0v = *(const f4v*)(Bm + (size_t)(n0 + r) * K + k0 + kk);
        f4v b1v = *(const f4v*)(Bm + (size_t)(n0 + r) * K + k0 + kk + 4);
        s16x8 bb;
#pragma unroll
        for (int i = 0; i < 4; ++i) { bb[i] = (short)f2bf(b0v[i]); bb[4 + i] = (short)f2bf(b1v[i]); }
        *(s16x8*)&Blds[r * 40 + kk] = bb;
        __syncthreads();
        s16x8 a = *(const s16x8*)&Alds[mrow * 40 + kq];
#pragma unroll
        for (int nt = 0; nt < 4; ++nt) {
            s16x8 b = *(const s16x8*)&Blds[(nt * 16 + (lane & 15)) * 40 + kq];
            acc[nt] = __builtin_amdgcn_mfma_f32_16x16x32_bf16(a, b, acc[nt], 0, 0, 0);
        }
        __syncthreads();
    }
    const int col = lane & 15;
    const int rq = (lane >> 4) * 4;
#pragma unroll
    for (int nt = 0; nt < 4; ++nt) {
        int n = n0 + nt * 16 + col;
        float bbv = bias[n];
#pragma unroll
        for (int rg = 0; rg < 4; ++rg) {
            int m = m0 + wave * 16 + rq + rg;
            C[(size_t)m * 3072 + n] = f2bf(acc[nt][rg] + bbv);
        }
    }
}

// ---------------- persistent encoder layer scan (one dir), MFMA recurrent GEMM ----------------
// 256 blocks x 64 threads. XCD-swizzled: xcd = blk&7 owns 8 j-slices (0.75MB of W
// per XCD L2). A-tile (16 batch rows x 1024) staged into swizzled LDS each step via
// agent-scope burst loads; weights read via normal (L2-resident) loads.
__global__ __launch_bounds__(64)
void enc_persist(const u16* __restrict__ W,      // [3072][1024] bf16 (this dir)
                 const float* __restrict__ bias, // [2][3072] (bih,bhh) this dir
                 const u16* __restrict__ xg,     // [6400][3072] bf16 this dir
                 float* __restrict__ h32,        // [2][64][1024] fp32 ping-pong
                 u16* __restrict__ hbf,          // [2][64][1024] bf16 ping-pong
                 u16* __restrict__ y,            // [6400][2048] bf16
                 int dir, unsigned* __restrict__ bar)
{
    __shared__ u16 Al[16 * 1024];                // 32 KB A-tile, XOR-swizzled
    const int lane = threadIdx.x;
    const int xcd = blockIdx.x & 7;
    const int slt = blockIdx.x >> 3;             // 0..31
    const int j0 = (xcd * 8 + (slt & 7)) * 16;   // 8 j-slices per XCD
    const int b0 = (slt >> 3) * 16;              // 4 batch quarters
    const int jc = j0 + (lane & 15);
    const int kq = (lane >> 4) * 8;
    const int arow = lane & 15;
    const int axor = (arow & 7) << 3;
    const float bhr = bias[3072 + jc];
    const float bhz = bias[4096 + jc];
    const float bhn = bias[5120 + jc];
    const u16* wR = W + (size_t)jc * 1024 + kq;
    const u16* wZ = W + (size_t)(1024 + jc) * 1024 + kq;
    const u16* wN = W + (size_t)(2048 + jc) * 1024 + kq;
    const int brow = b0 + (lane >> 4) * 4;

    for (int t = 0; t < 100; ++t) {
        f4v aR = {0.f, 0.f, 0.f, 0.f}, aZ = aR, aN = aR;
        if (t > 0) {
            // stage hbf[t&1] rows [b0,b0+16) into LDS: 2048 16B-chunks, grouped
            // bursts of 16 coherent 8B loads to keep the L3 round-trips pipelined
            const u16* hb = hbf + (size_t)(t & 1) * 65536 + (size_t)b0 * 1024;
            for (int g = 0; g < 4; ++g) {
                u64 tmp[16];
#pragma unroll
                for (int i = 0; i < 8; ++i) {
                    int c = lane + (g * 8 + i) * 64;          // chunk id
                    const u16* gp = hb + (size_t)(c >> 7) * 1024 + (c & 127) * 8;
                    tmp[2 * i]     = coh_load_u64(gp);
                    tmp[2 * i + 1] = coh_load_u64(gp + 4);
                }
#pragma unroll
                for (int i = 0; i < 8; ++i) {
                    int c = lane + (g * 8 + i) * 64;
                    int di = (c * 8) ^ (((c >> 7) & 7) << 3);  // 16B XOR swizzle
                    *(u64*)&Al[di]     = tmp[2 * i];
                    *(u64*)&Al[di + 4] = tmp[2 * i + 1];
                }
            }
            const int abase = arow * 1024 + kq;
            for (int k0 = 0; k0 < 1024; k0 += 32) {
                s16x8 av = *(const s16x8*)&Al[(abase + k0) ^ axor];
                s16x8 vR = *(const s16x8*)(wR + k0);
                s16x8 vZ = *(const s16x8*)(wZ + k0);
                s16x8 vN = *(const s16x8*)(wN + k0);
                aR = __builtin_amdgcn_mfma_f32_16x16x32_bf16(av, vR, aR, 0, 0, 0);
                aZ = __builtin_amdgcn_mfma_f32_16x16x32_bf16(av, vZ, aZ, 0, 0, 0);
                aN = __builtin_amdgcn_mfma_f32_16x16x32_bf16(av, vN, aN, 0, 0, 0);
            }
        }
        const float* h32r = h32 + (size_t)(t & 1) * 65536;
        float* h32w = h32 + (size_t)((t + 1) & 1) * 65536;
        u16*   hbw  = hbf + (size_t)((t + 1) & 1) * 65536;
#pragma unroll
        for (int r = 0; r < 4; ++r) {
            int b = brow + r;
            const u16* xr = xg + ((size_t)b * 100 + t) * 3072;
            float pr = bf2f((short)xr[jc]) + aR[r] + bhr;
            float pz = bf2f((short)xr[1024 + jc]) + aZ[r] + bhz;
            float pn = bf2f((short)xr[2048 + jc]);
            float hold = (t > 0) ? h32r[(size_t)b * 1024 + jc] : 0.f;
            float rg = 1.f / (1.f + expf(-pr));
            float zg = 1.f / (1.f + expf(-pz));
            float ng = tanhf(pn + rg * (aN[r] + bhn));
            float hnew = (1.f - zg) * ng + zg * hold;
            h32w[(size_t)b * 1024 + jc] = hnew;                    // block-local: normal
            coh_store_u16(&hbw[(size_t)b * 1024 + jc], f2bf(hnew)); // cross-block: write-through
            y[((size_t)b * 100 + t) * 2048 + dir * 1024 + jc] = f2bf(hnew);
        }
        if (t < 99) grid_barrier(bar, 256u * (unsigned)(t + 1));
    }
}

// ---------------- persistent decoder scan, H=K=2048, input gates = biases only ----------------
// 512 blocks x 64 threads (2 blocks/CU). block = (j-slice of 16, batch quarter of 16).
// XCD-swizzled: 16 j-slices per XCD = 3MB of W resident per XCD L2.
__global__ __launch_bounds__(64)
void dec_persist(const u16* __restrict__ W,     // [6144][2048] bf16
                 const float* __restrict__ db,  // [2][6144] fp32
                 float* __restrict__ h32,       // [2][64][2048] fp32 ping-pong
                 u16* __restrict__ hbf,         // [2][64][2048] bf16 ping-pong
                 u16* __restrict__ ys,          // [6400][2048] bf16
                 unsigned* __restrict__ bar)
{
    __shared__ u16 Al[16 * 2048];                // 64 KB A-tile, XOR-swizzled
    const int lane = threadIdx.x;
    const int xcd = blockIdx.x & 7;
    const int slt = blockIdx.x >> 3;             // 0..63
    const int j0 = (xcd * 16 + (slt & 15)) * 16; // 16 j-slices per XCD
    const int b0 = (slt >> 4) * 16;              // 4 batch quarters
    const int jc = j0 + (lane & 15);
    const int kq = (lane >> 4) * 8;
    const int arow = lane & 15;
    const int axor = (arow & 7) << 3;
    const float gir = db[jc]        + db[6144 + jc];
    const float giz = db[2048 + jc] + db[8192 + jc];
    const float gin = db[4096 + jc];
    const float bhn = db[10240 + jc];
    const u16* wR = W + (size_t)jc * 2048 + kq;
    const u16* wZ = W + (size_t)(2048 + jc) * 2048 + kq;
    const u16* wN = W + (size_t)(4096 + jc) * 2048 + kq;

    for (int t = 0; t < 100; ++t) {
        // stage hbf[t&1] rows [b0,b0+16) x 2048 into LDS (4096 chunks, 8 bursts)
        const u16* hb = hbf + (size_t)(t & 1) * 131072 + (size_t)b0 * 2048;
        for (int g = 0; g < 8; ++g) {
            u64 tmp[16];
#pragma unroll
            for (int i = 0; i < 8; ++i) {
                int c = lane + (g * 8 + i) * 64;
                const u16* gp = hb + (size_t)(c >> 8) * 2048 + (c & 255) * 8;
                tmp[2 * i]     = coh_load_u64(gp);
                tmp[2 * i + 1] = coh_load_u64(gp + 4);
            }
#pragma unroll
            for (int i = 0; i < 8; ++i) {
                int c = lane + (g * 8 + i) * 64;
                int di = (c * 8) ^ (((c >> 8) & 7) << 3);
                *(u64*)&Al[di]     = tmp[2 * i];
                *(u64*)&Al[di + 4] = tmp[2 * i + 1];
            }
        }
        f4v aR = {0.f, 0.f, 0.f, 0.f}, aZ = aR, aN = aR;
        const int abase = arow * 2048 + kq;
        for (int k0 = 0; k0 < 2048; k0 += 32) {
            s16x8 av = *(const s16x8*)&Al[(abase + k0) ^ axor];
            s16x8 vR = *(const s16x8*)(wR + k0);
            s16x8 vZ = *(const s16x8*)(wZ + k0);
            s16x8 vN = *(const s16x8*)(wN + k0);
            aR = __builtin_amdgcn_mfma_f32_16x16x32_bf16(av, vR, aR, 0, 0, 0);
            aZ = __builtin_amdgcn_mfma_f32_16x16x32_bf16(av, vZ, aZ, 0, 0, 0);
            aN = __builtin_amdgcn_mfma_f32_16x16x32_bf16(av, vN, aN, 0, 0, 0);
        }
        const float* h32r = h32 + (size_t)(t & 1) * 131072;
        float* h32w = h32 + (size_t)((t + 1) & 1) * 131072;
        u16*   hbw  = hbf + (size_t)((t + 1) & 1) * 131072;
#pragma unroll
        for (int r = 0; r < 4; ++r) {
            int b = b0 + (lane >> 4) * 4 + r;
            float pr = gir + aR[r];
            float pz = giz + aZ[r];
            float rg = 1.f / (1.f + expf(-pr));
            float zg = 1.f / (1.f + expf(-pz));
            float ng = tanhf(gin + rg * (aN[r] + bhn));
            float hold = h32r[(size_t)b * 2048 + jc];
            float hnew = (1.f - zg) * ng + zg * hold;
            h32w[(size_t)b * 2048 + jc] = hnew;                     // block-local
            coh_store_u16(&hbw[(size_t)b * 2048 + jc], f2bf(hnew)); // cross-block
            ys[((size_t)b * 100 + t) * 2048 + jc] = f2bf(hnew);
        }
        if (t < 99) grid_barrier(bar, 512u * (unsigned)(t + 1));
    }
}

// ---------------- gather enc_hidden = y[b, sl-1]; init decoder h ----------------
__global__ __launch_bounds__(256)
void gather_kernel(const int* __restrict__ seq_len, const u16* __restrict__ y,
                   float* __restrict__ out_enc, float* __restrict__ h32d,
                   u16* __restrict__ hbfd)
{
    int idx = blockIdx.x * 256 + threadIdx.x;   // < 131072
    int b = idx >> 11, j = idx & 2047;
    int s = seq_len[b];
    s = s < 1 ? 1 : (s > 100 ? 100 : s);
    u16 v = y[((size_t)b * 100 + (s - 1)) * 2048 + j];
    float f = bf2f((short)v);
    out_enc[idx] = f;
    h32d[idx] = f;     // pp0
    hbfd[idx] = v;     // pp0
}

// ---------------- output projection: dec_out[6400,75] = ys @ out_W^T + out_b ----------------
__global__ __launch_bounds__(256)
void proj_kernel(const u16* __restrict__ ys, const float* __restrict__ oW,
                 const float* __restrict__ oB, float* __restrict__ dec_out)
{
    const int r0 = blockIdx.x * 8;   // 800 blocks
    __shared__ float yl[8][2048];
    __shared__ float psum[3][8][76];
    for (int idx = threadIdx.x; idx < 2048; idx += 256) {
        int rr = idx >> 8, cc = idx & 255;
        s16x8 v = ((const s16x8*)(ys + (size_t)(r0 + rr) * 2048))[cc];
#pragma unroll
        for (int i = 0; i < 8; ++i) yl[rr][cc * 8 + i] = bf2f(v[i]);
    }
    __syncthreads();
    if (threadIdx.x < 225) {
        int d = threadIdx.x % 75, seg = threadIdx.x / 75;
        int ks = seg * 683, ke = ks + 683 < 2048 ? ks + 683 : 2048;
        const float* wr = oW + (size_t)d * 2048;
        float acc[8] = {0.f, 0.f, 0.f, 0.f, 0.f, 0.f, 0.f, 0.f};
        for (int k = ks; k < ke; ++k) {
            float w = wr[k];
#pragma unroll
            for (int r = 0; r < 8; ++r) acc[r] += yl[r][k] * w;
        }
#pragma unroll
        for (int r = 0; r < 8; ++r) psum[seg][r][d] = acc[r];
    }
    __syncthreads();
    for (int idx = threadIdx.x; idx < 600; idx += 256) {
        int r = idx / 75, d = idx % 75;
        dec_out[(size_t)(r0 + r) * 75 + d] =
            psum[0][r][d] + psum[1][r][d] + psum[2][r][d] + oB[d];
    }
}

// ================== round-3 fallback kernels (small-ws path) ==================
__device__ __forceinline__ void gemv3_f32(const float* __restrict__ w0,
                                          const float* __restrict__ w1,
                                          const float* __restrict__ w2,
                                          const f4v* __restrict__ hv,
                                          int n4, float& a0, float& a1, float& a2)
{
    for (int k = 0; k < n4; ++k) {
        f4v h4 = hv[k];
        f4v x0 = *(const f4v*)(w0 + k * 4);
        f4v x1 = *(const f4v*)(w1 + k * 4);
        f4v x2 = *(const f4v*)(w2 + k * 4);
        a0 += h4[0]*x0[0] + h4[1]*x0[1] + h4[2]*x0[2] + h4[3]*x0[3];
        a1 += h4[0]*x1[0] + h4[1]*x1[1] + h4[2]*x1[2] + h4[3]*x1[3];
        a2 += h4[0]*x2[0] + h4[1]*x2[1] + h4[2]*x2[2] + h4[3]*x2[3];
    }
}
__device__ __forceinline__ float dot_w32_v32(const float* __restrict__ w,
                                             const float* __restrict__ v, int n)
{
    float a = 0.f;
    for (int k = 0; k < n; ++k) a += w[k] * v[k];
    return a;
}
__device__ __forceinline__ float dot_w32_vbf(const float* __restrict__ w,
                                             const u16* __restrict__ v, int n8)
{
    float a = 0.f;
    for (int k8 = 0; k8 < n8; ++k8) {
        s16x8 v8 = *(const s16x8*)(v + k8 * 8);
        f4v w0 = *(const f4v*)(w + k8 * 8);
        f4v w1 = *(const f4v*)(w + k8 * 8 + 4);
        a += w0[0]*bf2f(v8[0]) + w0[1]*bf2f(v8[1]) + w0[2]*bf2f(v8[2]) + w0[3]*bf2f(v8[3])
           + w1[0]*bf2f(v8[4]) + w1[1]*bf2f(v8[5]) + w1[2]*bf2f(v8[6]) + w1[3]*bf2f(v8[7]);
    }
    return a;
}

__global__ __launch_bounds__(512)
void enc_scan_fused(int t,
                    const float* __restrict__ h_in, float* __restrict__ h_out,
                    const float* __restrict__ Whh, size_t whh_stride,
                    const float* __restrict__ Wih, size_t wih_stride, int Kin,
                    const float* __restrict__ xf, const u16* __restrict__ xb,
                    const float* __restrict__ bias, int bias_stride,
                    u16* __restrict__ y)
{
    const int dir = blockIdx.z;
    const int jt = blockIdx.x;
    const int b0 = blockIdx.y * 16;
    __shared__ float hlds[16][1024];
    const float* hin = h_in + (size_t)dir * 65536 + (size_t)b0 * 1024;
    if (t == 0) {
        f4v z = {0.f, 0.f, 0.f, 0.f};
        for (int idx = threadIdx.x; idx < 4096; idx += 512) ((f4v*)hlds)[idx] = z;
    } else {
        for (int idx = threadIdx.x; idx < 4096; idx += 512)
            ((f4v*)hlds)[idx] = ((const f4v*)hin)[idx];
    }
    __syncthreads();
    const int jl = threadIdx.x & 31;
    const int j  = jt * 32 + jl;
    const int bp = threadIdx.x >> 5;
    const float* wd = Whh + (size_t)dir * whh_stride;
    float a0 = 0.f, a1 = 0.f, a2 = 0.f;
    gemv3_f32(wd + (size_t)j * 1024, wd + (size_t)(1024 + j) * 1024,
              wd + (size_t)(2048 + j) * 1024, (const f4v*)&hlds[bp][0], 256, a0, a1, a2);
    const float* bd = bias + dir * bias_stride;
    const float* wi = Wih + (size_t)dir * wih_stride;
    const int gb = b0 + bp;
    float gi[3];
#pragma unroll
    for (int g = 0; g < 3; ++g) {
        const float* wr = wi + (size_t)(g * 1024 + j) * Kin;
        float s;
        if (xf) s = dot_w32_v32(wr, xf + ((size_t)gb * 100 + t) * Kin, Kin);
        else    s = dot_w32_vbf(wr, xb + ((size_t)gb * 100 + t) * Kin, Kin >> 3);
        gi[g] = bd[g * 1024 + j] + s;
    }
    const float* bhh = bd + 3072;
    float pr = gi[0] + a0 + bhh[j];
    float pz = gi[1] + a1 + bhh[1024 + j];
    float rg = 1.f / (1.f + expf(-pr));
    float zg = 1.f / (1.f + expf(-pz));
    float ng = tanhf(gi[2] + rg * (a2 + bhh[2048 + j]));
    float hold = hlds[bp][j];
    float hnew = (1.f - zg) * ng + zg * hold;
    h_out[(size_t)dir * 65536 + (size_t)gb * 1024 + j] = hnew;
    y[((size_t)gb * 100 + t) * 2048 + (size_t)dir * 1024 + j] = f2bf(hnew);
}

__global__ __launch_bounds__(512)
void dec_scan_step(int t, const float* __restrict__ h_in, float* __restrict__ h_out,
                   const float* __restrict__ Whh, const float* __restrict__ db,
                   u16* __restrict__ ys)
{
    const int jt = blockIdx.x;
    const int b0 = blockIdx.y * 16;
    __shared__ float hlds[16][1024];
    const int jl = threadIdx.x & 31;
    const int j  = jt * 32 + jl;
    const int bp = threadIdx.x >> 5;
    float a0 = 0.f, a1 = 0.f, a2 = 0.f;
    float hold = 0.f;
    for (int kc = 0; kc < 2; ++kc) {
        for (int idx = threadIdx.x; idx < 4096; idx += 512) {
            int rr = idx >> 8, cc = idx & 255;
            ((f4v*)hlds)[idx] = *(const f4v*)(h_in + (size_t)(b0 + rr) * 2048 + kc * 1024 + cc * 4);
        }
        __syncthreads();
        if ((j >> 10) == kc) hold = hlds[bp][j & 1023];
        const float* wb = Whh + kc * 1024;
        gemv3_f32(wb + (size_t)j * 2048, wb + (size_t)(2048 + j) * 2048,
                  wb + (size_t)(4096 + j) * 2048, (const f4v*)&hlds[bp][0], 256, a0, a1, a2);
        __syncthreads();
    }
    const int gb = b0 + bp;
    float pr = db[j] + a0 + db[6144 + j];
    float pz = db[2048 + j] + a1 + db[6144 + 2048 + j];
    float rg = 1.f / (1.f + expf(-pr));
    float zg = 1.f / (1.f + expf(-pz));
    float ng = tanhf(db[4096 + j] + rg * (a2 + db[6144 + 4096 + j]));
    float hnew = (1.f - zg) * ng + zg * hold;
    h_out[(size_t)gb * 2048 + j] = hnew;
    ys[((size_t)gb * 100 + t) * 2048 + j] = f2bf(hnew);
}

// ============================ launcher ============================
extern "C" void kernel_launch(void* const* d_in, const int* in_sizes, int n_in,
                              void* d_out, int out_size, void* d_ws, size_t ws_size,
                              hipStream_t stream)
{
    const float* x    = (const float*)d_in[0];
    const int*   sl   = (const int*)d_in[1];
    const float* Wih0 = (const float*)d_in[2];
    const float* Whh0 = (const float*)d_in[3];
    const float* b0   = (const float*)d_in[4];
    const float* Wih  = (const float*)d_in[5];
    const float* Whh  = (const float*)d_in[6];
    const float* bE   = (const float*)d_in[7];
    const float* dWhh = (const float*)d_in[9];
    const float* dB   = (const float*)d_in[10];
    const float* oW   = (const float*)d_in[11];
    const float* oB   = (const float*)d_in[12];
    float* out_enc = (float*)d_out;            // [64][2048]
    float* dec_out = (float*)d_out + 131072;   // [64][100][75]

    char* ws = (char*)d_ws;
    // ---- persistent-path layout (95.75 MiB) ----
    const size_t XG_OFF   = 0;            // [6400][3072] bf16 (one dir): 39,321,600
    const size_t YA_OFF   = 39321600;     // [6400][2048] bf16: 26,214,400
    const size_t YB_OFF   = 65536000;     // [6400][2048] bf16
    const size_t WC_OFF   = 91750400;     // [3072][1024] bf16: 6,291,456
    const size_t H32E_OFF = 98041856;     // [2][64][1024] f32: 524,288
    const size_t HBFE_OFF = 98566144;     // [2][64][1024] bf16: 262,144
    const size_t H32D_OFF = 98828288;     // [2][64][2048] f32: 1,048,576
    const size_t HBFD_OFF = 99876864;     // [2][64][2048] bf16: 524,288
    const size_t BAR_OFF  = 100401152;    // 256 B
    const size_t NEED     = 100401408;

    dim3 blk256(256), blk512(512), blk64(64);

    if (ws_size >= NEED) {
        u16*   xg   = (u16*)(ws + XG_OFF);
        u16*   y_a  = (u16*)(ws + YA_OFF);
        u16*   y_b  = (u16*)(ws + YB_OFF);
        u16*   Wc   = (u16*)(ws + WC_OFF);
        float* h32E = (float*)(ws + H32E_OFF);
        u16*   hbfE = (u16*)(ws + HBFE_OFF);
        float* h32D = (float*)(ws + H32D_OFF);
        u16*   hbfD = (u16*)(ws + HBFD_OFF);
        unsigned* bar = (unsigned*)(ws + BAR_OFF);

        zero_bar<<<1, 64, 0, stream>>>(bar, 16);

        int slot = 0;
        for (int l = 0; l < 3; ++l) {
            const u16* y_in = (l == 0) ? (const u16*)0 : ((l == 1) ? y_a : y_b);
            u16* y_out      = (l == 2) ? y_a : ((l == 0) ? y_a : y_b);
            for (int d = 0; d < 2; ++d) {
                const float* Wsrc = (l == 0) ? (Whh0 + (size_t)d * 3145728)
                                             : (Whh + ((size_t)(l - 1) * 2 + d) * 3145728);
                const float* bias = (l == 0) ? (b0 + (size_t)d * 6144)
                                             : (bE + (size_t)(l - 1) * 12288 + (size_t)d * 6144);
                cvt_bf16v<<<dim3(1024), blk256, 0, stream>>>(Wsrc, Wc, 786432);
                if (l == 0)
                    xg0_kernel<<<dim3(400), blk256, 0, stream>>>(
                        x, Wih0 + (size_t)d * 230400, b0 + (size_t)d * 6144, xg);
                else
                    xg_gemm<<<dim3(100, 48), blk256, 0, stream>>>(
                        y_in, Wih + ((size_t)(l - 1) * 2 + d) * 6291456, bias, xg, 2048);
                enc_persist<<<dim3(256), blk64, 0, stream>>>(
                    Wc, bias, xg, h32E, hbfE, y_out, d, bar + slot);
                ++slot;
            }
        }
        gather_kernel<<<dim3(512), blk256, 0, stream>>>(sl, y_a, out_enc, h32D, hbfD);
        u16* decW = (u16*)(ws + XG_OFF);   // reuse xg region (25.2 MB needed)
        cvt_bf16v<<<dim3(2048), blk256, 0, stream>>>(dWhh, decW, 3145728);
        dec_persist<<<dim3(512), blk64, 0, stream>>>(decW, dB, h32D, hbfD, y_b, bar + 6);
        proj_kernel<<<dim3(800), blk256, 0, stream>>>(y_b, oW, oB, dec_out);
    } else {
        // ---- fallback: round-3 fused path (~55 MiB) ----
        const size_t Y_B = 26214400;
        u16*   y_a  = (u16*)ws;
        u16*   y_b  = (u16*)(ws + Y_B);
        float* hE   = (float*)(ws + 2 * Y_B);                 // [2][2][64][1024] f32: 1 MB
        float* h32D = (float*)(ws + 2 * Y_B + 1048576);       // [2][64][2048] f32: 1 MB
        u16*   hbfD = (u16*)(ws + 2 * Y_B + 2097152);         // 0.5 MB

        for (int t = 0; t < 100; ++t) {
            int pp = t & 1;
            enc_scan_fused<<<dim3(32, 4, 2), blk512, 0, stream>>>(
                t, hE + (size_t)pp * 131072, hE + (size_t)(pp ^ 1) * 131072,
                Whh0, (size_t)3145728, Wih0, (size_t)230400, 75, x, (const u16*)0,
                b0, 6144, y_a);
        }
        for (int l = 0; l < 2; ++l) {
            const u16* yin = (l == 0) ? y_a : y_b;
            u16* yout      = (l == 0) ? y_b : y_a;
            for (int t = 0; t < 100; ++t) {
                int pp = t & 1;
                enc_scan_fused<<<dim3(32, 4, 2), blk512, 0, stream>>>(
                    t, hE + (size_t)pp * 131072, hE + (size_t)(pp ^ 1) * 131072,
                    Whh + (size_t)l * 2 * 3145728, (size_t)3145728,
                    Wih + (size_t)l * 2 * 6291456, (size_t)6291456, 2048,
                    (const float*)0, yin, bE + (size_t)l * 12288, 6144, yout);
            }
        }
        gather_kernel<<<dim3(512), blk256, 0, stream>>>(sl, y_a, out_enc, h32D, hbfD);
        for (int t = 0; t < 100; ++t) {
            int pp = t & 1;
            dec_scan_step<<<dim3(64, 4), blk512, 0, stream>>>(
                t, h32D + (size_t)pp * 131072, h32D + (size_t)(pp ^ 1) * 131072, dWhh, dB, y_b);
        }
        proj_kernel<<<dim3(800), blk256, 0, stream>>>(y_b, oW, oB, dec_out);
    }
}

// Round 3
// 15597.658 us; speedup vs baseline: 1.3944x; 1.2580x over previous
//
#include <hip/hip_runtime.h>
#include <math.h>

typedef unsigned short u16;
typedef unsigned long long u64;
typedef __attribute__((ext_vector_type(8))) short s16x8;
typedef __attribute__((ext_vector_type(4))) short s16x4;
typedef __attribute__((ext_vector_type(4))) float f4v;

__device__ __forceinline__ float bf2f(short u) {
    union { unsigned int i; float f; } v;
    v.i = ((unsigned int)(u16)u) << 16;
    return v.f;
}
__device__ __forceinline__ u16 f2bf(float f) {
    union { float f; unsigned int i; } v; v.f = f;
    unsigned int x = v.i;
    return (u16)((x + 0x7FFFu + ((x >> 16) & 1u)) >> 16);
}

// agent-scope (cross-XCD coherent, L2-bypassing) 8B load / 2B store
__device__ __forceinline__ u64 coh_load_u64(const u16* p) {
    return __hip_atomic_load((const u64*)p, __ATOMIC_RELAXED, __HIP_MEMORY_SCOPE_AGENT);
}
__device__ __forceinline__ void coh_store_u16(u16* p, u16 v) {
    __hip_atomic_store(p, v, __ATOMIC_RELAXED, __HIP_MEMORY_SCOPE_AGENT);
}

// ---------------- flag-array grid barrier (no RMW serialization) ----------------
// slot layout (128 u32 = 512B): flags[0..63] (one per block), epoch at [96].
// Arrival: parallel per-block stores to distinct words. Block 0 wave 0 sweeps the
// flags (1 per lane, pipelined) and publishes epoch; everyone polls epoch.
// __syncthreads() at entry drains each wave's vmcnt -> h stores ACKed before flag.
__device__ __forceinline__ void flag_barrier(unsigned* slot, int nblk, unsigned tgt) {
    __syncthreads();
    if (threadIdx.x == 0)
        __hip_atomic_store(&slot[blockIdx.x], tgt, __ATOMIC_RELAXED, __HIP_MEMORY_SCOPE_AGENT);
    if (blockIdx.x == 0 && (int)threadIdx.x < 64) {
        int spins = 0;
        for (;;) {
            int ok = 1;
            for (int i = (int)threadIdx.x; i < nblk; i += 64)
                ok &= (__hip_atomic_load(&slot[i], __ATOMIC_RELAXED,
                                         __HIP_MEMORY_SCOPE_AGENT) >= tgt);
            if (__all(ok)) break;
            __builtin_amdgcn_s_sleep(2);
            if (++spins > (1 << 20)) break;     // bail-out
        }
        if (threadIdx.x == 0)
            __hip_atomic_store(&slot[96], tgt, __ATOMIC_RELAXED, __HIP_MEMORY_SCOPE_AGENT);
    }
    int spins2 = 0;
    while (__hip_atomic_load(&slot[96], __ATOMIC_RELAXED, __HIP_MEMORY_SCOPE_AGENT) < tgt) {
        __builtin_amdgcn_s_sleep(1);
        if (++spins2 > (1 << 20)) break;        // bail-out
    }
    asm volatile("" ::: "memory");
}

__global__ void zero_bar(unsigned* p, int n) {
    int i = blockIdx.x * blockDim.x + threadIdx.x;
    if (i < n) p[i] = 0;
}

// ---------------- fp32 -> bf16 weight conversion ----------------
__global__ __launch_bounds__(256)
void cvt_bf16v(const float* __restrict__ src, u16* __restrict__ dst, int n4) {
    int i = blockIdx.x * 256 + threadIdx.x;
    int stride = gridDim.x * 256;
    for (; i < n4; i += stride) {
        f4v v = ((const f4v*)src)[i];
        s16x4 o;
#pragma unroll
        for (int j = 0; j < 4; ++j) o[j] = (short)f2bf(v[j]);
        ((s16x4*)dst)[i] = o;
    }
}

// ---------------- layer0 input gates (one dir): xg = x @ W^T + bih, K=75 ----------------
__global__ __launch_bounds__(256)
void xg0_kernel(const float* __restrict__ x,   // [6400][75]
                const float* __restrict__ W,   // [3072][75] (this dir)
                const float* __restrict__ bih, // [3072]
                u16* __restrict__ xg)          // [6400][3072]
{
    const int bt0 = blockIdx.x * 16;
    __shared__ float xl[16][76];
    for (int idx = threadIdx.x; idx < 16 * 75; idx += 256) {
        int r = idx / 75, k = idx % 75;
        xl[r][k] = x[(size_t)(bt0 + r) * 75 + k];
    }
    __syncthreads();
    for (int i = 0; i < 12; ++i) {
        int g = threadIdx.x + i * 256;
        const float* wr = W + (size_t)g * 75;
        float bv = bih[g];
        float acc[16];
#pragma unroll
        for (int r = 0; r < 16; ++r) acc[r] = bv;
        for (int k = 0; k < 75; ++k) {
            float w = wr[k];
#pragma unroll
            for (int r = 0; r < 16; ++r) acc[r] += xl[r][k] * w;
        }
#pragma unroll
        for (int r = 0; r < 16; ++r)
            xg[(size_t)(bt0 + r) * 3072 + g] = f2bf(acc[r]);
    }
}

// ---------------- MFMA bt-GEMM: C[6400,3072] = A(bf16)[6400,K] @ B(fp32)[3072,K]^T + bias ----------------
__global__ __launch_bounds__(256)
void xg_gemm(const u16* __restrict__ A, const float* __restrict__ Bm,
             const float* __restrict__ bias, u16* __restrict__ C, int K)
{
    __shared__ u16 Alds[64 * 40];
    __shared__ u16 Blds[64 * 40];
    const int m0 = blockIdx.x * 64;
    const int n0 = blockIdx.y * 64;
    const int wave = threadIdx.x >> 6;
    const int lane = threadIdx.x & 63;
    const int r = threadIdx.x >> 2;
    const int kk = (threadIdx.x & 3) * 8;
    const int mrow = wave * 16 + (lane & 15);
    const int kq = (lane >> 4) * 8;
    f4v acc[4];
#pragma unroll
    for (int nt = 0; nt < 4; ++nt) acc[nt] = (f4v){0.f, 0.f, 0.f, 0.f};

    for (int k0 = 0; k0 < K; k0 += 32) {
        *(s16x8*)&Alds[r * 40 + kk] = *(const s16x8*)(A + (size_t)(m0 + r) * K + k0 + kk);
        f4v b0v = *(const f4v*)(Bm + (size_t)(n0 + r) * K + k0 + kk);
        f4v b1v = *(const f4v*)(Bm + (size_t)(n0 + r) * K + k0 + kk + 4);
        s16x8 bb;
#pragma unroll
        for (int i = 0; i < 4; ++i) { bb[i] = (short)f2bf(b0v[i]); bb[4 + i] = (short)f2bf(b1v[i]); }
        *(s16x8*)&Blds[r * 40 + kk] = bb;
        __syncthreads();
        s16x8 a = *(const s16x8*)&Alds[mrow * 40 + kq];
#pragma unroll
        for (int nt = 0; nt < 4; ++nt) {
            s16x8 b = *(const s16x8*)&Blds[(nt * 16 + (lane & 15)) * 40 + kq];
            acc[nt] = __builtin_amdgcn_mfma_f32_16x16x32_bf16(a, b, acc[nt], 0, 0, 0);
        }
        __syncthreads();
    }
    const int col = lane & 15;
    const int rq = (lane >> 4) * 4;
#pragma unroll
    for (int nt = 0; nt < 4; ++nt) {
        int n = n0 + nt * 16 + col;
        float bbv = bias[n];
#pragma unroll
        for (int rg = 0; rg < 4; ++rg) {
            int m = m0 + wave * 16 + rq + rg;
            C[(size_t)m * 3072 + n] = f2bf(acc[nt][rg] + bbv);
        }
    }
}

// ---------------- persistent encoder layer scan (one dir), MFMA recurrent GEMM ----------------
// 64 blocks x 256 threads (4 waves). block = (j-group of 64, batch quarter of 16).
// XCD swizzle: xcd = blk&7 owns 2 j-groups (0.79 MB of W -> L2-resident).
// h kept in registers (same lane owns same (b,j) every step); cross-block h via
// agent-scope stores + one cooperative 16-deep burst of agent-scope loads -> LDS.
__global__ __launch_bounds__(256)
void enc_persist(const u16* __restrict__ W,      // [3072][1024] bf16 (this dir)
                 const float* __restrict__ bias, // [2][3072] (bih,bhh) this dir
                 const u16* __restrict__ xg,     // [6400][3072] bf16 this dir
                 u16* __restrict__ hbf,          // [2][64][1024] bf16 ping-pong
                 u16* __restrict__ y,            // [6400][2048] bf16
                 int dir, unsigned* __restrict__ bar)
{
    __shared__ u16 Al[16 * 1024];                // 32 KB A-tile, XOR-swizzled
    const int tid = threadIdx.x;
    const int lane = tid & 63;
    const int wv = tid >> 6;
    const int xcd = blockIdx.x & 7;
    const int jg = xcd * 2 + ((blockIdx.x >> 3) & 1);  // 16 j-groups of 64
    const int b0 = (blockIdx.x >> 4) * 16;             // 4 batch quarters
    const int jc = jg * 64 + wv * 16 + (lane & 15);
    const int kq = (lane >> 4) * 8;
    const int arow = lane & 15;
    const int axor = (arow & 7) << 3;
    const float bhr = bias[3072 + jc];
    const float bhz = bias[4096 + jc];
    const float bhn = bias[5120 + jc];
    const u16* wR = W + (size_t)jc * 1024 + kq;
    const u16* wZ = W + (size_t)(1024 + jc) * 1024 + kq;
    const u16* wN = W + (size_t)(2048 + jc) * 1024 + kq;
    const int brow = b0 + (lane >> 4) * 4;
    f4v hold = {0.f, 0.f, 0.f, 0.f};             // h0 = 0

    for (int t = 0; t < 100; ++t) {
        f4v aR = {0.f, 0.f, 0.f, 0.f}, aZ = aR, aN = aR;
        if (t > 0) {
            // cooperative stage: 2048 16B-chunks over 256 threads, ONE burst of 16 loads
            const u16* hb = hbf + (size_t)(t & 1) * 65536 + (size_t)b0 * 1024;
            u64 tmp[16];
#pragma unroll
            for (int g = 0; g < 8; ++g) {
                int c = tid + g * 256;
                const u16* gp = hb + (size_t)(c >> 7) * 1024 + (c & 127) * 8;
                tmp[2 * g]     = coh_load_u64(gp);
                tmp[2 * g + 1] = coh_load_u64(gp + 4);
            }
#pragma unroll
            for (int g = 0; g < 8; ++g) {
                int c = tid + g * 256;
                int di = (c * 8) ^ (((c >> 7) & 7) << 3);  // 16B XOR swizzle
                *(u64*)&Al[di]     = tmp[2 * g];
                *(u64*)&Al[di + 4] = tmp[2 * g + 1];
            }
            __syncthreads();
            const int abase = arow * 1024 + kq;
            for (int k0 = 0; k0 < 1024; k0 += 32) {
                s16x8 av = *(const s16x8*)&Al[(abase + k0) ^ axor];
                s16x8 vR = *(const s16x8*)(wR + k0);
                s16x8 vZ = *(const s16x8*)(wZ + k0);
                s16x8 vN = *(const s16x8*)(wN + k0);
                aR = __builtin_amdgcn_mfma_f32_16x16x32_bf16(av, vR, aR, 0, 0, 0);
                aZ = __builtin_amdgcn_mfma_f32_16x16x32_bf16(av, vZ, aZ, 0, 0, 0);
                aN = __builtin_amdgcn_mfma_f32_16x16x32_bf16(av, vN, aN, 0, 0, 0);
            }
        }
        u16* hbw = hbf + (size_t)((t + 1) & 1) * 65536;
#pragma unroll
        for (int r = 0; r < 4; ++r) {
            int b = brow + r;
            const u16* xr = xg + ((size_t)b * 100 + t) * 3072;
            float pr = bf2f((short)xr[jc]) + aR[r] + bhr;
            float pz = bf2f((short)xr[1024 + jc]) + aZ[r] + bhz;
            float pn = bf2f((short)xr[2048 + jc]);
            float rg = 1.f / (1.f + expf(-pr));
            float zg = 1.f / (1.f + expf(-pz));
            float ng = tanhf(pn + rg * (aN[r] + bhn));
            float hnew = (1.f - zg) * ng + zg * hold[r];
            hold[r] = hnew;
            coh_store_u16(&hbw[(size_t)b * 1024 + jc], f2bf(hnew));   // cross-block
            y[((size_t)b * 100 + t) * 2048 + dir * 1024 + jc] = f2bf(hnew);
        }
        if (t < 99) flag_barrier(bar, 64, (unsigned)(t + 1));
    }
}

// ---------------- persistent decoder scan, H=K=2048, input gates = biases only ----------------
// 64 blocks x 256 threads (4 waves x 2 j-slices). block = 128 j-cols x 16 batches.
// Per-XCD W footprint = 2 j-groups = 3.15 MB (L2-fit). h in registers.
__global__ __launch_bounds__(256)
void dec_persist(const u16* __restrict__ W,     // [6144][2048] bf16
                 const float* __restrict__ db,  // [2][6144] fp32
                 const float* __restrict__ h32, // [64][2048] fp32 init (pp0)
                 u16* __restrict__ hbf,         // [2][64][2048] bf16 ping-pong
                 u16* __restrict__ ys,          // [6400][2048] bf16
                 unsigned* __restrict__ bar)
{
    __shared__ u16 Al[16 * 2048];                // 64 KB A-tile, XOR-swizzled
    const int tid = threadIdx.x;
    const int lane = tid & 63;
    const int wv = tid >> 6;
    const int xcd = blockIdx.x & 7;
    const int jg = xcd * 2 + ((blockIdx.x >> 3) & 1);  // 16 j-groups of 128
    const int b0 = (blockIdx.x >> 4) * 16;             // 4 batch quarters
    const int kq = (lane >> 4) * 8;
    const int arow = lane & 15;
    const int axor = (arow & 7) << 3;

    int jcs[2];
    const u16 *wRp[2], *wZp[2], *wNp[2];
    float gir[2], giz[2], gin[2], bhn[2];
    f4v hold[2];
#pragma unroll
    for (int s = 0; s < 2; ++s) {
        int j = jg * 128 + wv * 32 + s * 16 + (lane & 15);
        jcs[s] = j;
        wRp[s] = W + (size_t)j * 2048 + kq;
        wZp[s] = W + (size_t)(2048 + j) * 2048 + kq;
        wNp[s] = W + (size_t)(4096 + j) * 2048 + kq;
        gir[s] = db[j] + db[6144 + j];
        giz[s] = db[2048 + j] + db[8192 + j];
        gin[s] = db[4096 + j];
        bhn[s] = db[10240 + j];
#pragma unroll
        for (int r = 0; r < 4; ++r)
            hold[s][r] = h32[(size_t)(b0 + (lane >> 4) * 4 + r) * 2048 + j];
    }

    for (int t = 0; t < 100; ++t) {
        // stage 16 rows x 2048 (64 KB): 4096 chunks, two bursts of 16 loads/thread
        const u16* hb = hbf + (size_t)(t & 1) * 131072 + (size_t)b0 * 2048;
#pragma unroll
        for (int h = 0; h < 2; ++h) {
            u64 tmp[16];
#pragma unroll
            for (int g = 0; g < 8; ++g) {
                int c = tid + (h * 8 + g) * 256;
                const u16* gp = hb + (size_t)(c >> 8) * 2048 + (c & 255) * 8;
                tmp[2 * g]     = coh_load_u64(gp);
                tmp[2 * g + 1] = coh_load_u64(gp + 4);
            }
#pragma unroll
            for (int g = 0; g < 8; ++g) {
                int c = tid + (h * 8 + g) * 256;
                int di = (c * 8) ^ (((c >> 8) & 7) << 3);
                *(u64*)&Al[di]     = tmp[2 * g];
                *(u64*)&Al[di + 4] = tmp[2 * g + 1];
            }
        }
        __syncthreads();
        f4v aR[2], aZ[2], aN[2];
#pragma unroll
        for (int s = 0; s < 2; ++s) {
            aR[s] = (f4v){0.f, 0.f, 0.f, 0.f}; aZ[s] = aR[s]; aN[s] = aR[s];
        }
        const int abase = arow * 2048 + kq;
        for (int k0 = 0; k0 < 2048; k0 += 32) {
            s16x8 av = *(const s16x8*)&Al[(abase + k0) ^ axor];
#pragma unroll
            for (int s = 0; s < 2; ++s) {
                s16x8 vR = *(const s16x8*)(wRp[s] + k0);
                s16x8 vZ = *(const s16x8*)(wZp[s] + k0);
                s16x8 vN = *(const s16x8*)(wNp[s] + k0);
                aR[s] = __builtin_amdgcn_mfma_f32_16x16x32_bf16(av, vR, aR[s], 0, 0, 0);
                aZ[s] = __builtin_amdgcn_mfma_f32_16x16x32_bf16(av, vZ, aZ[s], 0, 0, 0);
                aN[s] = __builtin_amdgcn_mfma_f32_16x16x32_bf16(av, vN, aN[s], 0, 0, 0);
            }
        }
        u16* hbw = hbf + (size_t)((t + 1) & 1) * 131072;
#pragma unroll
        for (int s = 0; s < 2; ++s) {
#pragma unroll
            for (int r = 0; r < 4; ++r) {
                int b = b0 + (lane >> 4) * 4 + r;
                float pr = gir[s] + aR[s][r];
                float pz = giz[s] + aZ[s][r];
                float rg = 1.f / (1.f + expf(-pr));
                float zg = 1.f / (1.f + expf(-pz));
                float ng = tanhf(gin[s] + rg * (aN[s][r] + bhn[s]));
                float hnew = (1.f - zg) * ng + zg * hold[s][r];
                hold[s][r] = hnew;
                coh_store_u16(&hbw[(size_t)b * 2048 + jcs[s]], f2bf(hnew));
                ys[((size_t)b * 100 + t) * 2048 + jcs[s]] = f2bf(hnew);
            }
        }
        if (t < 99) flag_barrier(bar, 64, (unsigned)(t + 1));
    }
}

// ---------------- gather enc_hidden = y[b, sl-1]; init decoder h ----------------
__global__ __launch_bounds__(256)
void gather_kernel(const int* __restrict__ seq_len, const u16* __restrict__ y,
                   float* __restrict__ out_enc, float* __restrict__ h32d,
                   u16* __restrict__ hbfd)
{
    int idx = blockIdx.x * 256 + threadIdx.x;   // < 131072
    int b = idx >> 11, j = idx & 2047;
    int s = seq_len[b];
    s = s < 1 ? 1 : (s > 100 ? 100 : s);
    u16 v = y[((size_t)b * 100 + (s - 1)) * 2048 + j];
    float f = bf2f((short)v);
    out_enc[idx] = f;
    h32d[idx] = f;     // pp0
    hbfd[idx] = v;     // pp0
}

// ---------------- output projection: dec_out[6400,75] = ys @ out_W^T + out_b ----------------
__global__ __launch_bounds__(256)
void proj_kernel(const u16* __restrict__ ys, const float* __restrict__ oW,
                 const float* __restrict__ oB, float* __restrict__ dec_out)
{
    const int r0 = blockIdx.x * 8;   // 800 blocks
    __shared__ float yl[8][2048];
    __shared__ float psum[3][8][76];
    for (int idx = threadIdx.x; idx < 2048; idx += 256) {
        int rr = idx >> 8, cc = idx & 255;
        s16x8 v = ((const s16x8*)(ys + (size_t)(r0 + rr) * 2048))[cc];
#pragma unroll
        for (int i = 0; i < 8; ++i) yl[rr][cc * 8 + i] = bf2f(v[i]);
    }
    __syncthreads();
    if (threadIdx.x < 225) {
        int d = threadIdx.x % 75, seg = threadIdx.x / 75;
        int ks = seg * 683, ke = ks + 683 < 2048 ? ks + 683 : 2048;
        const float* wr = oW + (size_t)d * 2048;
        float acc[8] = {0.f, 0.f, 0.f, 0.f, 0.f, 0.f, 0.f, 0.f};
        for (int k = ks; k < ke; ++k) {
            float w = wr[k];
#pragma unroll
            for (int r = 0; r < 8; ++r) acc[r] += yl[r][k] * w;
        }
#pragma unroll
        for (int r = 0; r < 8; ++r) psum[seg][r][d] = acc[r];
    }
    __syncthreads();
    for (int idx = threadIdx.x; idx < 600; idx += 256) {
        int r = idx / 75, d = idx % 75;
        dec_out[(size_t)(r0 + r) * 75 + d] =
            psum[0][r][d] + psum[1][r][d] + psum[2][r][d] + oB[d];
    }
}

// ================== round-3 fallback kernels (small-ws path) ==================
__device__ __forceinline__ void gemv3_f32(const float* __restrict__ w0,
                                          const float* __restrict__ w1,
                                          const float* __restrict__ w2,
                                          const f4v* __restrict__ hv,
                                          int n4, float& a0, float& a1, float& a2)
{
    for (int k = 0; k < n4; ++k) {
        f4v h4 = hv[k];
        f4v x0 = *(const f4v*)(w0 + k * 4);
        f4v x1 = *(const f4v*)(w1 + k * 4);
        f4v x2 = *(const f4v*)(w2 + k * 4);
        a0 += h4[0]*x0[0] + h4[1]*x0[1] + h4[2]*x0[2] + h4[3]*x0[3];
        a1 += h4[0]*x1[0] + h4[1]*x1[1] + h4[2]*x1[2] + h4[3]*x1[3];
        a2 += h4[0]*x2[0] + h4[1]*x2[1] + h4[2]*x2[2] + h4[3]*x2[3];
    }
}
__device__ __forceinline__ float dot_w32_v32(const float* __restrict__ w,
                                             const float* __restrict__ v, int n)
{
    float a = 0.f;
    for (int k = 0; k < n; ++k) a += w[k] * v[k];
    return a;
}
__device__ __forceinline__ float dot_w32_vbf(const float* __restrict__ w,
                                             const u16* __restrict__ v, int n8)
{
    float a = 0.f;
    for (int k8 = 0; k8 < n8; ++k8) {
        s16x8 v8 = *(const s16x8*)(v + k8 * 8);
        f4v w0 = *(const f4v*)(w + k8 * 8);
        f4v w1 = *(const f4v*)(w + k8 * 8 + 4);
        a += w0[0]*bf2f(v8[0]) + w0[1]*bf2f(v8[1]) + w0[2]*bf2f(v8[2]) + w0[3]*bf2f(v8[3])
           + w1[0]*bf2f(v8[4]) + w1[1]*bf2f(v8[5]) + w1[2]*bf2f(v8[6]) + w1[3]*bf2f(v8[7]);
    }
    return a;
}

__global__ __launch_bounds__(512)
void enc_scan_fused(int t,
                    const float* __restrict__ h_in, float* __restrict__ h_out,
                    const float* __restrict__ Whh, size_t whh_stride,
                    const float* __restrict__ Wih, size_t wih_stride, int Kin,
                    const float* __restrict__ xf, const u16* __restrict__ xb,
                    const float* __restrict__ bias, int bias_stride,
                    u16* __restrict__ y)
{
    const int dir = blockIdx.z;
    const int jt = blockIdx.x;
    const int b0 = blockIdx.y * 16;
    __shared__ float hlds[16][1024];
    const float* hin = h_in + (size_t)dir * 65536 + (size_t)b0 * 1024;
    if (t == 0) {
        f4v z = {0.f, 0.f, 0.f, 0.f};
        for (int idx = threadIdx.x; idx < 4096; idx += 512) ((f4v*)hlds)[idx] = z;
    } else {
        for (int idx = threadIdx.x; idx < 4096; idx += 512)
            ((f4v*)hlds)[idx] = ((const f4v*)hin)[idx];
    }
    __syncthreads();
    const int jl = threadIdx.x & 31;
    const int j  = jt * 32 + jl;
    const int bp = threadIdx.x >> 5;
    const float* wd = Whh + (size_t)dir * whh_stride;
    float a0 = 0.f, a1 = 0.f, a2 = 0.f;
    gemv3_f32(wd + (size_t)j * 1024, wd + (size_t)(1024 + j) * 1024,
              wd + (size_t)(2048 + j) * 1024, (const f4v*)&hlds[bp][0], 256, a0, a1, a2);
    const float* bd = bias + dir * bias_stride;
    const float* wi = Wih + (size_t)dir * wih_stride;
    const int gb = b0 + bp;
    float gi[3];
#pragma unroll
    for (int g = 0; g < 3; ++g) {
        const float* wr = wi + (size_t)(g * 1024 + j) * Kin;
        float s;
        if (xf) s = dot_w32_v32(wr, xf + ((size_t)gb * 100 + t) * Kin, Kin);
        else    s = dot_w32_vbf(wr, xb + ((size_t)gb * 100 + t) * Kin, Kin >> 3);
        gi[g] = bd[g * 1024 + j] + s;
    }
    const float* bhh = bd + 3072;
    float pr = gi[0] + a0 + bhh[j];
    float pz = gi[1] + a1 + bhh[1024 + j];
    float rg = 1.f / (1.f + expf(-pr));
    float zg = 1.f / (1.f + expf(-pz));
    float ng = tanhf(gi[2] + rg * (a2 + bhh[2048 + j]));
    float hold = hlds[bp][j];
    float hnew = (1.f - zg) * ng + zg * hold;
    h_out[(size_t)dir * 65536 + (size_t)gb * 1024 + j] = hnew;
    y[((size_t)gb * 100 + t) * 2048 + (size_t)dir * 1024 + j] = f2bf(hnew);
}

__global__ __launch_bounds__(512)
void dec_scan_step(int t, const float* __restrict__ h_in, float* __restrict__ h_out,
                   const float* __restrict__ Whh, const float* __restrict__ db,
                   u16* __restrict__ ys)
{
    const int jt = blockIdx.x;
    const int b0 = blockIdx.y * 16;
    __shared__ float hlds[16][1024];
    const int jl = threadIdx.x & 31;
    const int j  = jt * 32 + jl;
    const int bp = threadIdx.x >> 5;
    float a0 = 0.f, a1 = 0.f, a2 = 0.f;
    float hold = 0.f;
    for (int kc = 0; kc < 2; ++kc) {
        for (int idx = threadIdx.x; idx < 4096; idx += 512) {
            int rr = idx >> 8, cc = idx & 255;
            ((f4v*)hlds)[idx] = *(const f4v*)(h_in + (size_t)(b0 + rr) * 2048 + kc * 1024 + cc * 4);
        }
        __syncthreads();
        if ((j >> 10) == kc) hold = hlds[bp][j & 1023];
        const float* wb = Whh + kc * 1024;
        gemv3_f32(wb + (size_t)j * 2048, wb + (size_t)(2048 + j) * 2048,
                  wb + (size_t)(4096 + j) * 2048, (const f4v*)&hlds[bp][0], 256, a0, a1, a2);
        __syncthreads();
    }
    const int gb = b0 + bp;
    float pr = db[j] + a0 + db[6144 + j];
    float pz = db[2048 + j] + a1 + db[6144 + 2048 + j];
    float rg = 1.f / (1.f + expf(-pr));
    float zg = 1.f / (1.f + expf(-pz));
    float ng = tanhf(db[4096 + j] + rg * (a2 + db[6144 + 4096 + j]));
    float hnew = (1.f - zg) * ng + zg * hold;
    h_out[(size_t)gb * 2048 + j] = hnew;
    ys[((size_t)gb * 100 + t) * 2048 + j] = f2bf(hnew);
}

// ============================ launcher ============================
extern "C" void kernel_launch(void* const* d_in, const int* in_sizes, int n_in,
                              void* d_out, int out_size, void* d_ws, size_t ws_size,
                              hipStream_t stream)
{
    const float* x    = (const float*)d_in[0];
    const int*   sl   = (const int*)d_in[1];
    const float* Wih0 = (const float*)d_in[2];
    const float* Whh0 = (const float*)d_in[3];
    const float* b0   = (const float*)d_in[4];
    const float* Wih  = (const float*)d_in[5];
    const float* Whh  = (const float*)d_in[6];
    const float* bE   = (const float*)d_in[7];
    const float* dWhh = (const float*)d_in[9];
    const float* dB   = (const float*)d_in[10];
    const float* oW   = (const float*)d_in[11];
    const float* oB   = (const float*)d_in[12];
    float* out_enc = (float*)d_out;            // [64][2048]
    float* dec_out = (float*)d_out + 131072;   // [64][100][75]

    char* ws = (char*)d_ws;
    // ---- persistent-path layout ----
    const size_t XG_OFF   = 0;            // [6400][3072] bf16 (one dir): 39,321,600
    const size_t YA_OFF   = 39321600;     // [6400][2048] bf16: 26,214,400
    const size_t YB_OFF   = 65536000;     // [6400][2048] bf16
    const size_t WC_OFF   = 91750400;     // [3072][1024] bf16: 6,291,456
    const size_t H32E_OFF = 98041856;     // (unused, kept for layout stability)
    const size_t HBFE_OFF = 98566144;     // [2][64][1024] bf16: 262,144
    const size_t H32D_OFF = 98828288;     // [2][64][2048] f32: 1,048,576
    const size_t HBFD_OFF = 99876864;     // [2][64][2048] bf16: 524,288
    const size_t BAR_OFF  = 100401152;    // 7 slots x 512 B = 3584 B
    const size_t NEED     = 100404736;
    (void)H32E_OFF;

    dim3 blk256(256), blk512(512);

    if (ws_size >= NEED) {
        u16*   xg   = (u16*)(ws + XG_OFF);
        u16*   y_a  = (u16*)(ws + YA_OFF);
        u16*   y_b  = (u16*)(ws + YB_OFF);
        u16*   Wc   = (u16*)(ws + WC_OFF);
        u16*   hbfE = (u16*)(ws + HBFE_OFF);
        float* h32D = (float*)(ws + H32D_OFF);
        u16*   hbfD = (u16*)(ws + HBFD_OFF);
        unsigned* bar = (unsigned*)(ws + BAR_OFF);

        zero_bar<<<dim3(4), blk256, 0, stream>>>(bar, 896);

        int slot = 0;
        for (int l = 0; l < 3; ++l) {
            const u16* y_in = (l == 0) ? (const u16*)0 : ((l == 1) ? y_a : y_b);
            u16* y_out      = (l == 2) ? y_a : ((l == 0) ? y_a : y_b);
            for (int d = 0; d < 2; ++d) {
                const float* Wsrc = (l == 0) ? (Whh0 + (size_t)d * 3145728)
                                             : (Whh + ((size_t)(l - 1) * 2 + d) * 3145728);
                const float* bias = (l == 0) ? (b0 + (size_t)d * 6144)
                                             : (bE + (size_t)(l - 1) * 12288 + (size_t)d * 6144);
                cvt_bf16v<<<dim3(1024), blk256, 0, stream>>>(Wsrc, Wc, 786432);
                if (l == 0)
                    xg0_kernel<<<dim3(400), blk256, 0, stream>>>(
                        x, Wih0 + (size_t)d * 230400, b0 + (size_t)d * 6144, xg);
                else
                    xg_gemm<<<dim3(100, 48), blk256, 0, stream>>>(
                        y_in, Wih + ((size_t)(l - 1) * 2 + d) * 6291456, bias, xg, 2048);
                enc_persist<<<dim3(64), blk256, 0, stream>>>(
                    Wc, bias, xg, hbfE, y_out, d, bar + (size_t)slot * 128);
                ++slot;
            }
        }
        gather_kernel<<<dim3(512), blk256, 0, stream>>>(sl, y_a, out_enc, h32D, hbfD);
        u16* decW = (u16*)(ws + XG_OFF);   // reuse xg region (25.2 MB needed)
        cvt_bf16v<<<dim3(2048), blk256, 0, stream>>>(dWhh, decW, 3145728);
        dec_persist<<<dim3(64), blk256, 0, stream>>>(decW, dB, h32D, hbfD, y_b,
                                                     bar + (size_t)6 * 128);
        proj_kernel<<<dim3(800), blk256, 0, stream>>>(y_b, oW, oB, dec_out);
    } else {
        // ---- fallback: round-3 fused path (~55 MiB) ----
        const size_t Y_B = 26214400;
        u16*   y_a  = (u16*)ws;
        u16*   y_b  = (u16*)(ws + Y_B);
        float* hE   = (float*)(ws + 2 * Y_B);                 // [2][2][64][1024] f32: 1 MB
        float* h32D = (float*)(ws + 2 * Y_B + 1048576);       // [2][64][2048] f32: 1 MB
        u16*   hbfD = (u16*)(ws + 2 * Y_B + 2097152);         // 0.5 MB

        for (int t = 0; t < 100; ++t) {
            int pp = t & 1;
            enc_scan_fused<<<dim3(32, 4, 2), blk512, 0, stream>>>(
                t, hE + (size_t)pp * 131072, hE + (size_t)(pp ^ 1) * 131072,
                Whh0, (size_t)3145728, Wih0, (size_t)230400, 75, x, (const u16*)0,
                b0, 6144, y_a);
        }
        for (int l = 0; l < 2; ++l) {
            const u16* yin = (l == 0) ? y_a : y_b;
            u16* yout      = (l == 0) ? y_b : y_a;
            for (int t = 0; t < 100; ++t) {
                int pp = t & 1;
                enc_scan_fused<<<dim3(32, 4, 2), blk512, 0, stream>>>(
                    t, hE + (size_t)pp * 131072, hE + (size_t)(pp ^ 1) * 131072,
                    Whh + (size_t)l * 2 * 3145728, (size_t)3145728,
                    Wih + (size_t)l * 2 * 6291456, (size_t)6291456, 2048,
                    (const float*)0, yin, bE + (size_t)l * 12288, 6144, yout);
            }
        }
        gather_kernel<<<dim3(512), blk256, 0, stream>>>(sl, y_a, out_enc, h32D, hbfD);
        for (int t = 0; t < 100; ++t) {
            int pp = t & 1;
            dec_scan_step<<<dim3(64, 4), blk512, 0, stream>>>(
                t, h32D + (size_t)pp * 131072, h32D + (size_t)(pp ^ 1) * 131072, dWhh, dB, y_b);
        }
        proj_kernel<<<dim3(800), blk256, 0, stream>>>(y_b, oW, oB, dec_out);
    }
}

// Round 4
// 9092.810 us; speedup vs baseline: 2.3920x; 1.7154x over previous
//
#include <hip/hip_runtime.h>
#include <math.h>

typedef unsigned short u16;
typedef unsigned long long u64;
typedef __attribute__((ext_vector_type(8))) short s16x8;
typedef __attribute__((ext_vector_type(4))) short s16x4;
typedef __attribute__((ext_vector_type(4))) float f4v;

__device__ __forceinline__ float bf2f(short u) {
    union { unsigned int i; float f; } v;
    v.i = ((unsigned int)(u16)u) << 16;
    return v.f;
}
__device__ __forceinline__ u16 f2bf(float f) {
    union { float f; unsigned int i; } v; v.f = f;
    unsigned int x = v.i;
    return (u16)((x + 0x7FFFu + ((x >> 16) & 1u)) >> 16);
}

// agent-scope (cross-XCD coherent, L2-bypassing) loads/stores
__device__ __forceinline__ u64 coh_load_u64(const u16* p) {
    return __hip_atomic_load((const u64*)p, __ATOMIC_RELAXED, __HIP_MEMORY_SCOPE_AGENT);
}
__device__ __forceinline__ void coh_store_u64(u16* p, u64 v) {
    __hip_atomic_store((u64*)p, v, __ATOMIC_RELAXED, __HIP_MEMORY_SCOPE_AGENT);
}

// ---------------- flag-array grid barrier (no RMW; thread0-only epoch poll) ----------------
// slot = 256 u32 (1 KB): flags[0..nblk-1], epoch at [192].
__device__ __forceinline__ void flag_barrier(unsigned* slot, int nblk, unsigned tgt) {
    __syncthreads();                       // all waves' stores drained (vmcnt0) before flag
    if (threadIdx.x == 0)
        __hip_atomic_store(&slot[blockIdx.x], tgt, __ATOMIC_RELAXED, __HIP_MEMORY_SCOPE_AGENT);
    if (blockIdx.x == 0 && (int)threadIdx.x < 64) {
        int spins = 0;
        for (;;) {
            int ok = 1;
            for (int i = (int)threadIdx.x; i < nblk; i += 64)
                ok &= (__hip_atomic_load(&slot[i], __ATOMIC_RELAXED,
                                         __HIP_MEMORY_SCOPE_AGENT) >= tgt);
            if (__all(ok)) break;
            __builtin_amdgcn_s_sleep(2);
            if (++spins > (1 << 20)) break;     // bail-out
        }
        if (threadIdx.x == 0)
            __hip_atomic_store(&slot[192], tgt, __ATOMIC_RELAXED, __HIP_MEMORY_SCOPE_AGENT);
    }
    if (threadIdx.x == 0) {
        int spins2 = 0;
        while (__hip_atomic_load(&slot[192], __ATOMIC_RELAXED, __HIP_MEMORY_SCOPE_AGENT) < tgt) {
            __builtin_amdgcn_s_sleep(1);
            if (++spins2 > (1 << 20)) break;    // bail-out
        }
    }
    __syncthreads();
    asm volatile("" ::: "memory");
}

__global__ void zero_bar(unsigned* p, int n) {
    int i = blockIdx.x * blockDim.x + threadIdx.x;
    if (i < n) p[i] = 0;
}

// ---------------- fp32 -> bf16 weight conversion (fallback path helper) ----------------
__global__ __launch_bounds__(256)
void cvt_bf16v(const float* __restrict__ src, u16* __restrict__ dst, int n4) {
    int i = blockIdx.x * 256 + threadIdx.x;
    int stride = gridDim.x * 256;
    for (; i < n4; i += stride) {
        f4v v = ((const f4v*)src)[i];
        s16x4 o;
#pragma unroll
        for (int j = 0; j < 4; ++j) o[j] = (short)f2bf(v[j]);
        ((s16x4*)dst)[i] = o;
    }
}

// ---------------- fp32 -> bf16 MFMA-fragment packing ----------------
// src: fp32 [3*H][K] (H = JT*16, K = KB*32). dst fragment f=(g*JT+jt)*KB+kb is
// 64 lanes x 8 bf16 contiguous (1 KB): lane l, elem e -> row g*H+jt*16+(l&15),
// col kb*32+(l>>4)*8+e. K-loop weight loads become 1KB coalesced streams.
__global__ __launch_bounds__(256)
void cvt_pack(const float* __restrict__ src, u16* __restrict__ dst,
              int JT, int KB, int K)
{
    int fid = blockIdx.x * 4 + (threadIdx.x >> 6);
    int lane = threadIdx.x & 63;
    int nf = 3 * JT * KB;
    if (fid >= nf) return;
    int g = fid / (JT * KB);
    int rem = fid - g * JT * KB;
    int jt = rem / KB;
    int kb = rem - jt * KB;
    int j = jt * 16 + (lane & 15);
    int k = kb * 32 + (lane >> 4) * 8;
    const float* s = src + ((size_t)g * JT * 16 + j) * K + k;
    f4v a = *(const f4v*)s;
    f4v b = *(const f4v*)(s + 4);
    s16x8 o;
#pragma unroll
    for (int i = 0; i < 4; ++i) { o[i] = (short)f2bf(a[i]); o[4 + i] = (short)f2bf(b[i]); }
    *(s16x8*)(dst + (size_t)fid * 512 + lane * 8) = o;
}

// ---------------- layer0 input gates (one dir): xg = x @ W^T + bih, K=75 ----------------
__global__ __launch_bounds__(256)
void xg0_kernel(const float* __restrict__ x,   // [6400][75]
                const float* __restrict__ W,   // [3072][75] (this dir)
                const float* __restrict__ bih, // [3072]
                u16* __restrict__ xg)          // [6400][3072]
{
    const int bt0 = blockIdx.x * 16;
    __shared__ float xl[16][76];
    for (int idx = threadIdx.x; idx < 16 * 75; idx += 256) {
        int r = idx / 75, k = idx % 75;
        xl[r][k] = x[(size_t)(bt0 + r) * 75 + k];
    }
    __syncthreads();
    for (int i = 0; i < 12; ++i) {
        int g = threadIdx.x + i * 256;
        const float* wr = W + (size_t)g * 75;
        float bv = bih[g];
        float acc[16];
#pragma unroll
        for (int r = 0; r < 16; ++r) acc[r] = bv;
        for (int k = 0; k < 75; ++k) {
            float w = wr[k];
#pragma unroll
            for (int r = 0; r < 16; ++r) acc[r] += xl[r][k] * w;
        }
#pragma unroll
        for (int r = 0; r < 16; ++r)
            xg[(size_t)(bt0 + r) * 3072 + g] = f2bf(acc[r]);
    }
}

// ---------------- MFMA bt-GEMM: C[6400,3072] = A(bf16)[6400,K] @ B(fp32)[3072,K]^T + bias ----------------
__global__ __launch_bounds__(256)
void xg_gemm(const u16* __restrict__ A, const float* __restrict__ Bm,
             const float* __restrict__ bias, u16* __restrict__ C, int K)
{
    __shared__ u16 Alds[64 * 40];
    __shared__ u16 Blds[64 * 40];
    const int m0 = blockIdx.x * 64;
    const int n0 = blockIdx.y * 64;
    const int wave = threadIdx.x >> 6;
    const int lane = threadIdx.x & 63;
    const int r = threadIdx.x >> 2;
    const int kk = (threadIdx.x & 3) * 8;
    const int mrow = wave * 16 + (lane & 15);
    const int kq = (lane >> 4) * 8;
    f4v acc[4];
#pragma unroll
    for (int nt = 0; nt < 4; ++nt) acc[nt] = (f4v){0.f, 0.f, 0.f, 0.f};

    for (int k0 = 0; k0 < K; k0 += 32) {
        *(s16x8*)&Alds[r * 40 + kk] = *(const s16x8*)(A + (size_t)(m0 + r) * K + k0 + kk);
        f4v b0v = *(const f4v*)(Bm + (size_t)(n0 + r) * K + k0 + kk);
        f4v b1v = *(const f4v*)(Bm + (size_t)(n0 + r) * K + k0 + kk + 4);
        s16x8 bb;
#pragma unroll
        for (int i = 0; i < 4; ++i) { bb[i] = (short)f2bf(b0v[i]); bb[4 + i] = (short)f2bf(b1v[i]); }
        *(s16x8*)&Blds[r * 40 + kk] = bb;
        __syncthreads();
        s16x8 a = *(const s16x8*)&Alds[mrow * 40 + kq];
#pragma unroll
        for (int nt = 0; nt < 4; ++nt) {
            s16x8 b = *(const s16x8*)&Blds[(nt * 16 + (lane & 15)) * 40 + kq];
            acc[nt] = __builtin_amdgcn_mfma_f32_16x16x32_bf16(a, b, acc[nt], 0, 0, 0);
        }
        __syncthreads();
    }
    const int col = lane & 15;
    const int rq = (lane >> 4) * 4;
#pragma unroll
    for (int nt = 0; nt < 4; ++nt) {
        int n = n0 + nt * 16 + col;
        float bbv = bias[n];
#pragma unroll
        for (int rg = 0; rg < 4; ++rg) {
            int m = m0 + wave * 16 + rq + rg;
            C[(size_t)m * 3072 + n] = f2bf(acc[nt][rg] + bbv);
        }
    }
}

// ---------------- persistent encoder layer scan (one dir), packed-weight MFMA ----------------
// 64 blocks x 256 threads (4 waves x 16 j). block = (j-group of 64, batch quarter).
// Weights packed fragment-linear -> 1KB coalesced loads, register prefetch.
__global__ __launch_bounds__(256)
void enc_persist(const u16* __restrict__ Wp,     // packed [3][64][32] frags (bf16)
                 const float* __restrict__ bias, // [2][3072] (bih,bhh) this dir
                 const u16* __restrict__ xg,     // [6400][3072] bf16 this dir
                 u16* __restrict__ hbf,          // [2][64][1024] bf16 ping-pong
                 u16* __restrict__ y,            // [6400][2048] bf16
                 int dir, unsigned* __restrict__ bar)
{
    __shared__ u16 Al[16 * 1024];                // 32 KB A-tile, XOR-swizzled
    __shared__ u16 OutE[16 * 64];                // 2 KB h-out staging
    const int tid = threadIdx.x;
    const int lane = tid & 63;
    const int wv = tid >> 6;
    const int xcd = blockIdx.x & 7;
    const int jg = xcd * 2 + ((blockIdx.x >> 3) & 1);  // 16 j-groups of 64
    const int b0 = (blockIdx.x >> 4) * 16;             // 4 batch quarters
    const int jc = jg * 64 + wv * 16 + (lane & 15);
    const int jt = jg * 4 + wv;                        // packed j-tile (JT=64, KB=32)
    const int kq = (lane >> 4) * 8;
    const int arow = lane & 15;
    const int axor = (arow & 7) << 3;
    const float bhr = bias[3072 + jc];
    const float bhz = bias[4096 + jc];
    const float bhn = bias[5120 + jc];
    const u16* pR = Wp + ((size_t)(0 * 64 + jt) * 32) * 512 + lane * 8;
    const u16* pZ = Wp + ((size_t)(1 * 64 + jt) * 32) * 512 + lane * 8;
    const u16* pN = Wp + ((size_t)(2 * 64 + jt) * 32) * 512 + lane * 8;
    const int brow = b0 + (lane >> 4) * 4;
    f4v hold = {0.f, 0.f, 0.f, 0.f};             // h0 = 0

    for (int t = 0; t < 100; ++t) {
        f4v aR = {0.f, 0.f, 0.f, 0.f}, aZ = aR, aN = aR;
        if (t > 0) {
            // cooperative stage: 2048 16B-chunks over 256 threads, one 16-deep burst
            const u16* hb = hbf + (size_t)(t & 1) * 65536 + (size_t)b0 * 1024;
            u64 tmp[16];
#pragma unroll
            for (int g = 0; g < 8; ++g) {
                int c = tid + g * 256;
                const u16* gp = hb + (size_t)(c >> 7) * 1024 + (c & 127) * 8;
                tmp[2 * g]     = coh_load_u64(gp);
                tmp[2 * g + 1] = coh_load_u64(gp + 4);
            }
#pragma unroll
            for (int g = 0; g < 8; ++g) {
                int c = tid + g * 256;
                int di = (c * 8) ^ (((c >> 7) & 7) << 3);  // 16B XOR swizzle
                *(u64*)&Al[di]     = tmp[2 * g];
                *(u64*)&Al[di + 4] = tmp[2 * g + 1];
            }
            __syncthreads();
            const int abase = arow * 1024 + kq;
            s16x8 cR = *(const s16x8*)(pR);
            s16x8 cZ = *(const s16x8*)(pZ);
            s16x8 cN = *(const s16x8*)(pN);
            for (int kb = 0; kb < 32; ++kb) {
                int kn = (kb + 1 < 32) ? kb + 1 : kb;
                s16x8 nR = *(const s16x8*)(pR + (size_t)kn * 512);
                s16x8 nZ = *(const s16x8*)(pZ + (size_t)kn * 512);
                s16x8 nN = *(const s16x8*)(pN + (size_t)kn * 512);
                s16x8 av = *(const s16x8*)&Al[(abase + kb * 32) ^ axor];
                aR = __builtin_amdgcn_mfma_f32_16x16x32_bf16(av, cR, aR, 0, 0, 0);
                aZ = __builtin_amdgcn_mfma_f32_16x16x32_bf16(av, cZ, aZ, 0, 0, 0);
                aN = __builtin_amdgcn_mfma_f32_16x16x32_bf16(av, cN, aN, 0, 0, 0);
                cR = nR; cZ = nZ; cN = nN;
            }
        }
#pragma unroll
        for (int r = 0; r < 4; ++r) {
            int b = brow + r;
            const u16* xr = xg + ((size_t)b * 100 + t) * 3072;
            float pr = bf2f((short)xr[jc]) + aR[r] + bhr;
            float pz = bf2f((short)xr[1024 + jc]) + aZ[r] + bhz;
            float pn = bf2f((short)xr[2048 + jc]);
            float rg = 1.f / (1.f + expf(-pr));
            float zg = 1.f / (1.f + expf(-pz));
            float ng = tanhf(pn + rg * (aN[r] + bhn));
            float hnew = (1.f - zg) * ng + zg * hold[r];
            hold[r] = hnew;
            OutE[((lane >> 4) * 4 + r) * 64 + wv * 16 + (lane & 15)] = f2bf(hnew);
        }
        __syncthreads();
        if (tid < 128) {     // coalesced cross-block + y stores (16 b x 64 j tile)
            int bl = tid >> 3, jl = (tid & 7) * 8;
            s16x8 v = *(const s16x8*)&OutE[bl * 64 + jl];
            const u64* pv = (const u64*)&v;
            u16* hw = hbf + (size_t)((t + 1) & 1) * 65536
                    + (size_t)(b0 + bl) * 1024 + jg * 64 + jl;
            coh_store_u64(hw, pv[0]);
            coh_store_u64(hw + 4, pv[1]);
            *(s16x8*)(y + ((size_t)(b0 + bl) * 100 + t) * 2048
                        + (size_t)dir * 1024 + jg * 64 + jl) = v;
        }
        if (t < 99) flag_barrier(bar, 64, (unsigned)(t + 1));
    }
}

// ---------------- persistent decoder scan, H=K=2048, packed-weight MFMA ----------------
// 128 blocks x 256 threads (4 waves x 16 j). block = (j-group of 64, batch quarter).
// Per-XCD W footprint = 4 j-groups = 3.15 MB (L2-fit). h in registers.
__global__ __launch_bounds__(256)
void dec_persist(const u16* __restrict__ Wp,    // packed [3][128][64] frags (bf16)
                 const float* __restrict__ db,  // [2][6144] fp32
                 const float* __restrict__ h32, // [64][2048] fp32 init (pp0)
                 u16* __restrict__ hbf,         // [2][64][2048] bf16 ping-pong
                 u16* __restrict__ ys,          // [6400][2048] bf16
                 unsigned* __restrict__ bar)
{
    __shared__ u16 Al[16 * 2048];                // 64 KB A-tile, XOR-swizzled
    __shared__ u16 OutD[16 * 64];                // 2 KB h-out staging
    const int tid = threadIdx.x;
    const int lane = tid & 63;
    const int wv = tid >> 6;
    const int xcd = blockIdx.x & 7;
    const int idx = blockIdx.x >> 3;                   // 0..15
    const int jg = xcd * 4 + (idx & 3);                // 32 j-groups of 64
    const int b0 = (idx >> 2) * 16;                    // 4 batch quarters
    const int jc = jg * 64 + wv * 16 + (lane & 15);
    const int jt = jg * 4 + wv;                        // packed j-tile (JT=128, KB=64)
    const int kq = (lane >> 4) * 8;
    const int arow = lane & 15;
    const int axor = (arow & 7) << 3;
    const float gir = db[jc]        + db[6144 + jc];
    const float giz = db[2048 + jc] + db[8192 + jc];
    const float gin = db[4096 + jc];
    const float bhn = db[10240 + jc];
    const u16* pR = Wp + ((size_t)(0 * 128 + jt) * 64) * 512 + lane * 8;
    const u16* pZ = Wp + ((size_t)(1 * 128 + jt) * 64) * 512 + lane * 8;
    const u16* pN = Wp + ((size_t)(2 * 128 + jt) * 64) * 512 + lane * 8;
    f4v hold;
#pragma unroll
    for (int r = 0; r < 4; ++r)
        hold[r] = h32[(size_t)(b0 + (lane >> 4) * 4 + r) * 2048 + jc];

    for (int t = 0; t < 100; ++t) {
        // stage 16 rows x 2048 (64 KB): 4096 chunks, two 16-deep bursts
        const u16* hb = hbf + (size_t)(t & 1) * 131072 + (size_t)b0 * 2048;
#pragma unroll
        for (int h = 0; h < 2; ++h) {
            u64 tmp[16];
#pragma unroll
            for (int g = 0; g < 8; ++g) {
                int c = tid + (h * 8 + g) * 256;
                const u16* gp = hb + (size_t)(c >> 8) * 2048 + (c & 255) * 8;
                tmp[2 * g]     = coh_load_u64(gp);
                tmp[2 * g + 1] = coh_load_u64(gp + 4);
            }
#pragma unroll
            for (int g = 0; g < 8; ++g) {
                int c = tid + (h * 8 + g) * 256;
                int di = (c * 8) ^ (((c >> 8) & 7) << 3);
                *(u64*)&Al[di]     = tmp[2 * g];
                *(u64*)&Al[di + 4] = tmp[2 * g + 1];
            }
        }
        __syncthreads();
        f4v aR = {0.f, 0.f, 0.f, 0.f}, aZ = aR, aN = aR;
        const int abase = arow * 2048 + kq;
        s16x8 cR = *(const s16x8*)(pR);
        s16x8 cZ = *(const s16x8*)(pZ);
        s16x8 cN = *(const s16x8*)(pN);
        for (int kb = 0; kb < 64; ++kb) {
            int kn = (kb + 1 < 64) ? kb + 1 : kb;
            s16x8 nR = *(const s16x8*)(pR + (size_t)kn * 512);
            s16x8 nZ = *(const s16x8*)(pZ + (size_t)kn * 512);
            s16x8 nN = *(const s16x8*)(pN + (size_t)kn * 512);
            s16x8 av = *(const s16x8*)&Al[(abase + kb * 32) ^ axor];
            aR = __builtin_amdgcn_mfma_f32_16x16x32_bf16(av, cR, aR, 0, 0, 0);
            aZ = __builtin_amdgcn_mfma_f32_16x16x32_bf16(av, cZ, aZ, 0, 0, 0);
            aN = __builtin_amdgcn_mfma_f32_16x16x32_bf16(av, cN, aN, 0, 0, 0);
            cR = nR; cZ = nZ; cN = nN;
        }
        __syncthreads();     // Al done being read; OutE region reuse safe
#pragma unroll
        for (int r = 0; r < 4; ++r) {
            float pr = gir + aR[r];
            float pz = giz + aZ[r];
            float rg = 1.f / (1.f + expf(-pr));
            float zg = 1.f / (1.f + expf(-pz));
            float ng = tanhf(gin + rg * (aN[r] + bhn));
            float hnew = (1.f - zg) * ng + zg * hold[r];
            hold[r] = hnew;
            OutD[((lane >> 4) * 4 + r) * 64 + wv * 16 + (lane & 15)] = f2bf(hnew);
        }
        __syncthreads();
        if (tid < 128) {     // coalesced cross-block + ys stores (16 b x 64 j tile)
            int bl = tid >> 3, jl = (tid & 7) * 8;
            s16x8 v = *(const s16x8*)&OutD[bl * 64 + jl];
            const u64* pv = (const u64*)&v;
            u16* hw = hbf + (size_t)((t + 1) & 1) * 131072
                    + (size_t)(b0 + bl) * 2048 + jg * 64 + jl;
            coh_store_u64(hw, pv[0]);
            coh_store_u64(hw + 4, pv[1]);
            *(s16x8*)(ys + ((size_t)(b0 + bl) * 100 + t) * 2048 + jg * 64 + jl) = v;
        }
        if (t < 99) flag_barrier(bar, 128, (unsigned)(t + 1));
    }
}

// ---------------- gather enc_hidden = y[b, sl-1]; init decoder h ----------------
__global__ __launch_bounds__(256)
void gather_kernel(const int* __restrict__ seq_len, const u16* __restrict__ y,
                   float* __restrict__ out_enc, float* __restrict__ h32d,
                   u16* __restrict__ hbfd)
{
    int idx = blockIdx.x * 256 + threadIdx.x;   // < 131072
    int b = idx >> 11, j = idx & 2047;
    int s = seq_len[b];
    s = s < 1 ? 1 : (s > 100 ? 100 : s);
    u16 v = y[((size_t)b * 100 + (s - 1)) * 2048 + j];
    float f = bf2f((short)v);
    out_enc[idx] = f;
    h32d[idx] = f;     // pp0
    hbfd[idx] = v;     // pp0
}

// ---------------- output projection: dec_out[6400,75] = ys @ out_W^T + out_b ----------------
__global__ __launch_bounds__(256)
void proj_kernel(const u16* __restrict__ ys, const float* __restrict__ oW,
                 const float* __restrict__ oB, float* __restrict__ dec_out)
{
    const int r0 = blockIdx.x * 8;   // 800 blocks
    __shared__ float yl[8][2048];
    __shared__ float psum[3][8][76];
    for (int idx = threadIdx.x; idx < 2048; idx += 256) {
        int rr = idx >> 8, cc = idx & 255;
        s16x8 v = ((const s16x8*)(ys + (size_t)(r0 + rr) * 2048))[cc];
#pragma unroll
        for (int i = 0; i < 8; ++i) yl[rr][cc * 8 + i] = bf2f(v[i]);
    }
    __syncthreads();
    if (threadIdx.x < 225) {
        int d = threadIdx.x % 75, seg = threadIdx.x / 75;
        int ks = seg * 683, ke = ks + 683 < 2048 ? ks + 683 : 2048;
        const float* wr = oW + (size_t)d * 2048;
        float acc[8] = {0.f, 0.f, 0.f, 0.f, 0.f, 0.f, 0.f, 0.f};
        for (int k = ks; k < ke; ++k) {
            float w = wr[k];
#pragma unroll
            for (int r = 0; r < 8; ++r) acc[r] += yl[r][k] * w;
        }
#pragma unroll
        for (int r = 0; r < 8; ++r) psum[seg][r][d] = acc[r];
    }
    __syncthreads();
    for (int idx = threadIdx.x; idx < 600; idx += 256) {
        int r = idx / 75, d = idx % 75;
        dec_out[(size_t)(r0 + r) * 75 + d] =
            psum[0][r][d] + psum[1][r][d] + psum[2][r][d] + oB[d];
    }
}

// ================== fallback kernels (small-ws path) ==================
__device__ __forceinline__ void gemv3_f32(const float* __restrict__ w0,
                                          const float* __restrict__ w1,
                                          const float* __restrict__ w2,
                                          const f4v* __restrict__ hv,
                                          int n4, float& a0, float& a1, float& a2)
{
    for (int k = 0; k < n4; ++k) {
        f4v h4 = hv[k];
        f4v x0 = *(const f4v*)(w0 + k * 4);
        f4v x1 = *(const f4v*)(w1 + k * 4);
        f4v x2 = *(const f4v*)(w2 + k * 4);
        a0 += h4[0]*x0[0] + h4[1]*x0[1] + h4[2]*x0[2] + h4[3]*x0[3];
        a1 += h4[0]*x1[0] + h4[1]*x1[1] + h4[2]*x1[2] + h4[3]*x1[3];
        a2 += h4[0]*x2[0] + h4[1]*x2[1] + h4[2]*x2[2] + h4[3]*x2[3];
    }
}
__device__ __forceinline__ float dot_w32_v32(const float* __restrict__ w,
                                             const float* __restrict__ v, int n)
{
    float a = 0.f;
    for (int k = 0; k < n; ++k) a += w[k] * v[k];
    return a;
}
__device__ __forceinline__ float dot_w32_vbf(const float* __restrict__ w,
                                             const u16* __restrict__ v, int n8)
{
    float a = 0.f;
    for (int k8 = 0; k8 < n8; ++k8) {
        s16x8 v8 = *(const s16x8*)(v + k8 * 8);
        f4v w0 = *(const f4v*)(w + k8 * 8);
        f4v w1 = *(const f4v*)(w + k8 * 8 + 4);
        a += w0[0]*bf2f(v8[0]) + w0[1]*bf2f(v8[1]) + w0[2]*bf2f(v8[2]) + w0[3]*bf2f(v8[3])
           + w1[0]*bf2f(v8[4]) + w1[1]*bf2f(v8[5]) + w1[2]*bf2f(v8[6]) + w1[3]*bf2f(v8[7]);
    }
    return a;
}

__global__ __launch_bounds__(512)
void enc_scan_fused(int t,
                    const float* __restrict__ h_in, float* __restrict__ h_out,
                    const float* __restrict__ Whh, size_t whh_stride,
                    const float* __restrict__ Wih, size_t wih_stride, int Kin,
                    const float* __restrict__ xf, const u16* __restrict__ xb,
                    const float* __restrict__ bias, int bias_stride,
                    u16* __restrict__ y)
{
    const int dir = blockIdx.z;
    const int jt = blockIdx.x;
    const int b0 = blockIdx.y * 16;
    __shared__ float hlds[16][1024];
    const float* hin = h_in + (size_t)dir * 65536 + (size_t)b0 * 1024;
    if (t == 0) {
        f4v z = {0.f, 0.f, 0.f, 0.f};
        for (int idx = threadIdx.x; idx < 4096; idx += 512) ((f4v*)hlds)[idx] = z;
    } else {
        for (int idx = threadIdx.x; idx < 4096; idx += 512)
            ((f4v*)hlds)[idx] = ((const f4v*)hin)[idx];
    }
    __syncthreads();
    const int jl = threadIdx.x & 31;
    const int j  = jt * 32 + jl;
    const int bp = threadIdx.x >> 5;
    const float* wd = Whh + (size_t)dir * whh_stride;
    float a0 = 0.f, a1 = 0.f, a2 = 0.f;
    gemv3_f32(wd + (size_t)j * 1024, wd + (size_t)(1024 + j) * 1024,
              wd + (size_t)(2048 + j) * 1024, (const f4v*)&hlds[bp][0], 256, a0, a1, a2);
    const float* bd = bias + dir * bias_stride;
    const float* wi = Wih + (size_t)dir * wih_stride;
    const int gb = b0 + bp;
    float gi[3];
#pragma unroll
    for (int g = 0; g < 3; ++g) {
        const float* wr = wi + (size_t)(g * 1024 + j) * Kin;
        float s;
        if (xf) s = dot_w32_v32(wr, xf + ((size_t)gb * 100 + t) * Kin, Kin);
        else    s = dot_w32_vbf(wr, xb + ((size_t)gb * 100 + t) * Kin, Kin >> 3);
        gi[g] = bd[g * 1024 + j] + s;
    }
    const float* bhh = bd + 3072;
    float pr = gi[0] + a0 + bhh[j];
    float pz = gi[1] + a1 + bhh[1024 + j];
    float rg = 1.f / (1.f + expf(-pr));
    float zg = 1.f / (1.f + expf(-pz));
    float ng = tanhf(gi[2] + rg * (a2 + bhh[2048 + j]));
    float hold = hlds[bp][j];
    float hnew = (1.f - zg) * ng + zg * hold;
    h_out[(size_t)dir * 65536 + (size_t)gb * 1024 + j] = hnew;
    y[((size_t)gb * 100 + t) * 2048 + (size_t)dir * 1024 + j] = f2bf(hnew);
}

__global__ __launch_bounds__(512)
void dec_scan_step(int t, const float* __restrict__ h_in, float* __restrict__ h_out,
                   const float* __restrict__ Whh, const float* __restrict__ db,
                   u16* __restrict__ ys)
{
    const int jt = blockIdx.x;
    const int b0 = blockIdx.y * 16;
    __shared__ float hlds[16][1024];
    const int jl = threadIdx.x & 31;
    const int j  = jt * 32 + jl;
    const int bp = threadIdx.x >> 5;
    float a0 = 0.f, a1 = 0.f, a2 = 0.f;
    float hold = 0.f;
    for (int kc = 0; kc < 2; ++kc) {
        for (int idx = threadIdx.x; idx < 4096; idx += 512) {
            int rr = idx >> 8, cc = idx & 255;
            ((f4v*)hlds)[idx] = *(const f4v*)(h_in + (size_t)(b0 + rr) * 2048 + kc * 1024 + cc * 4);
        }
        __syncthreads();
        if ((j >> 10) == kc) hold = hlds[bp][j & 1023];
        const float* wb = Whh + kc * 1024;
        gemv3_f32(wb + (size_t)j * 2048, wb + (size_t)(2048 + j) * 2048,
                  wb + (size_t)(4096 + j) * 2048, (const f4v*)&hlds[bp][0], 256, a0, a1, a2);
        __syncthreads();
    }
    const int gb = b0 + bp;
    float pr = db[j] + a0 + db[6144 + j];
    float pz = db[2048 + j] + a1 + db[6144 + 2048 + j];
    float rg = 1.f / (1.f + expf(-pr));
    float zg = 1.f / (1.f + expf(-pz));
    float ng = tanhf(db[4096 + j] + rg * (a2 + db[6144 + 4096 + j]));
    float hnew = (1.f - zg) * ng + zg * hold;
    h_out[(size_t)gb * 2048 + j] = hnew;
    ys[((size_t)gb * 100 + t) * 2048 + j] = f2bf(hnew);
}

// ============================ launcher ============================
extern "C" void kernel_launch(void* const* d_in, const int* in_sizes, int n_in,
                              void* d_out, int out_size, void* d_ws, size_t ws_size,
                              hipStream_t stream)
{
    const float* x    = (const float*)d_in[0];
    const int*   sl   = (const int*)d_in[1];
    const float* Wih0 = (const float*)d_in[2];
    const float* Whh0 = (const float*)d_in[3];
    const float* b0   = (const float*)d_in[4];
    const float* Wih  = (const float*)d_in[5];
    const float* Whh  = (const float*)d_in[6];
    const float* bE   = (const float*)d_in[7];
    const float* dWhh = (const float*)d_in[9];
    const float* dB   = (const float*)d_in[10];
    const float* oW   = (const float*)d_in[11];
    const float* oB   = (const float*)d_in[12];
    float* out_enc = (float*)d_out;            // [64][2048]
    float* dec_out = (float*)d_out + 131072;   // [64][100][75]

    char* ws = (char*)d_ws;
    // ---- persistent-path layout ----
    const size_t XG_OFF   = 0;            // [6400][3072] bf16 (one dir): 39,321,600
    const size_t YA_OFF   = 39321600;     // [6400][2048] bf16: 26,214,400
    const size_t YB_OFF   = 65536000;     // [6400][2048] bf16
    const size_t WC_OFF   = 91750400;     // packed enc W bf16: 6,291,456
    const size_t HBFE_OFF = 98566144;     // [2][64][1024] bf16: 262,144
    const size_t H32D_OFF = 98828288;     // [2][64][2048] f32: 1,048,576
    const size_t HBFD_OFF = 99876864;     // [2][64][2048] bf16: 524,288
    const size_t BAR_OFF  = 100401152;    // 7 slots x 1 KB
    const size_t NEED     = 100408320;

    dim3 blk256(256), blk512(512);

    if (ws_size >= NEED) {
        u16*   xg   = (u16*)(ws + XG_OFF);
        u16*   y_a  = (u16*)(ws + YA_OFF);
        u16*   y_b  = (u16*)(ws + YB_OFF);
        u16*   Wc   = (u16*)(ws + WC_OFF);
        u16*   hbfE = (u16*)(ws + HBFE_OFF);
        float* h32D = (float*)(ws + H32D_OFF);
        u16*   hbfD = (u16*)(ws + HBFD_OFF);
        unsigned* bar = (unsigned*)(ws + BAR_OFF);

        zero_bar<<<dim3(7), blk256, 0, stream>>>(bar, 1792);

        int slot = 0;
        for (int l = 0; l < 3; ++l) {
            const u16* y_in = (l == 0) ? (const u16*)0 : ((l == 1) ? y_a : y_b);
            u16* y_out      = (l == 2) ? y_a : ((l == 0) ? y_a : y_b);
            for (int d = 0; d < 2; ++d) {
                const float* Wsrc = (l == 0) ? (Whh0 + (size_t)d * 3145728)
                                             : (Whh + ((size_t)(l - 1) * 2 + d) * 3145728);
                const float* bias = (l == 0) ? (b0 + (size_t)d * 6144)
                                             : (bE + (size_t)(l - 1) * 12288 + (size_t)d * 6144);
                cvt_pack<<<dim3(1536), blk256, 0, stream>>>(Wsrc, Wc, 64, 32, 1024);
                if (l == 0)
                    xg0_kernel<<<dim3(400), blk256, 0, stream>>>(
                        x, Wih0 + (size_t)d * 230400, b0 + (size_t)d * 6144, xg);
                else
                    xg_gemm<<<dim3(100, 48), blk256, 0, stream>>>(
                        y_in, Wih + ((size_t)(l - 1) * 2 + d) * 6291456, bias, xg, 2048);
                enc_persist<<<dim3(64), blk256, 0, stream>>>(
                    Wc, bias, xg, hbfE, y_out, d, bar + (size_t)slot * 256);
                ++slot;
            }
        }
        gather_kernel<<<dim3(512), blk256, 0, stream>>>(sl, y_a, out_enc, h32D, hbfD);
        u16* decW = (u16*)(ws + XG_OFF);   // reuse xg region (25.2 MB needed)
        cvt_pack<<<dim3(6144), blk256, 0, stream>>>(dWhh, decW, 128, 64, 2048);
        dec_persist<<<dim3(128), blk256, 0, stream>>>(decW, dB, h32D, hbfD, y_b,
                                                      bar + (size_t)6 * 256);
        proj_kernel<<<dim3(800), blk256, 0, stream>>>(y_b, oW, oB, dec_out);
    } else {
        // ---- fallback: fused path (~55 MiB) ----
        const size_t Y_B = 26214400;
        u16*   y_a  = (u16*)ws;
        u16*   y_b  = (u16*)(ws + Y_B);
        float* hE   = (float*)(ws + 2 * Y_B);                 // [2][2][64][1024] f32: 1 MB
        float* h32D = (float*)(ws + 2 * Y_B + 1048576);       // [2][64][2048] f32: 1 MB
        u16*   hbfD = (u16*)(ws + 2 * Y_B + 2097152);         // 0.5 MB

        for (int t = 0; t < 100; ++t) {
            int pp = t & 1;
            enc_scan_fused<<<dim3(32, 4, 2), blk512, 0, stream>>>(
                t, hE + (size_t)pp * 131072, hE + (size_t)(pp ^ 1) * 131072,
                Whh0, (size_t)3145728, Wih0, (size_t)230400, 75, x, (const u16*)0,
                b0, 6144, y_a);
        }
        for (int l = 0; l < 2; ++l) {
            const u16* yin = (l == 0) ? y_a : y_b;
            u16* yout      = (l == 0) ? y_b : y_a;
            for (int t = 0; t < 100; ++t) {
                int pp = t & 1;
                enc_scan_fused<<<dim3(32, 4, 2), blk512, 0, stream>>>(
                    t, hE + (size_t)pp * 131072, hE + (size_t)(pp ^ 1) * 131072,
                    Whh + (size_t)l * 2 * 3145728, (size_t)3145728,
                    Wih + (size_t)l * 2 * 6291456, (size_t)6291456, 2048,
                    (const float*)0, yin, bE + (size_t)l * 12288, 6144, yout);
            }
        }
        gather_kernel<<<dim3(512), blk256, 0, stream>>>(sl, y_a, out_enc, h32D, hbfD);
        for (int t = 0; t < 100; ++t) {
            int pp = t & 1;
            dec_scan_step<<<dim3(64, 4), blk512, 0, stream>>>(
                t, h32D + (size_t)pp * 131072, h32D + (size_t)(pp ^ 1) * 131072, dWhh, dB, y_b);
        }
        proj_kernel<<<dim3(800), blk256, 0, stream>>>(y_b, oW, oB, dec_out);
    }
}